// Round 4
// baseline (360.715 us; speedup 1.0000x reference)
//
#include <hip/hip_runtime.h>
#include <math.h>

#define B    8
#define L    4096
#define H    256
#define N2   32
#define NL   4
#define O2   512   // 2H
#define BLK  64    // scan block length
#define NBLK 64    // L/BLK
#define TVP  136   // TVc row stride (elems): 64 T + 64 Vc + 8 pad
#define MJP  72    // Mm row stride
#define UTP  72    // uT/ST LDS row stride (u16), 144B = 16B-mult
#define INP  68    // INC LDS row stride (f32), 272B = 16B-mult
#define TL2  32    // k_gemm l-tile (was 64: 2 blocks/CU -> 4 blocks/CU overlap)
#define YPAD 264   // k_gemm yS row stride (u16)
#define URP2 40    // k_gemm residual-tile LDS row stride (u16), 80B = 16B-mult

typedef __attribute__((ext_vector_type(8))) short short8;
typedef __attribute__((ext_vector_type(4))) float f32x4;

__device__ __forceinline__ unsigned short f2bf(float f)
{
    unsigned int u = __float_as_uint(f);
    unsigned int r = (u + 0x7fffu + ((u >> 16) & 1u)) >> 16;
    return (unsigned short)r;
}

__device__ __forceinline__ float bf2f(unsigned short v)
{
    return __uint_as_float(((unsigned int)v) << 16);
}

// fast GELU: x * sigmoid(1.5957691216(x + 0.044715 x^3)) — max err ~2e-3
__device__ __forceinline__ float gelu_f(float x)
{
    float t = 1.59576912161f * fmaf(0.044715f * x * x, x, x);
    return x / (1.f + __expf(-t));
}

// ---------------- merged setup: [0,512) wcvt | [512,1536) mats | [1536,5632) tr_xu ----------------
__global__ __launch_bounds__(256) void k_setup(
    const float* __restrict__ x, const float* __restrict__ log_dt,
    const float* __restrict__ log_Ar, const float* __restrict__ A_im,
    const float* __restrict__ C_re, const float* __restrict__ C_im,
    const float* __restrict__ Dv, const float* __restrict__ Wout,
    unsigned short* __restrict__ Wb, unsigned short* __restrict__ TVc,
    unsigned short* __restrict__ Mm, float2* __restrict__ w64c,
    unsigned short* __restrict__ u)
{
    // union: tr_xu uses 8.7 KB f32 tile; mats uses 27.6 KB staging
    __shared__ __align__(16) unsigned char smem_raw[27648];
    const int bid = blockIdx.x;
    const int t = threadIdx.x;

    if (bid < 512) {
        // ---- Wout fp32 -> bf16 ----
        int idx = (bid * 256 + t) * 4;
        float4 v = *(const float4*)(Wout + idx);
        ushort4 o;
        o.x = f2bf(v.x); o.y = f2bf(v.y); o.z = f2bf(v.z); o.w = f2bf(v.w);
        *(ushort4*)(Wb + idx) = o;
    } else if (bid < 1536) {
        // ---- build per-(layer,h): T|Vc, M, w^64 — one id per block ----
        unsigned short* tvS = (unsigned short*)smem_raw;      // [64*TVP] 17408 B
        unsigned short* mmS = tvS + BLK * TVP;                // [64*MJP]  9216 B
        float* kbS = (float*)(mmS + BLK * MJP);               // [64]       256 B
        float* cS  = kbS + BLK;                               // [6*32]     768 B
        const int id = bid - 512;                             // [0, 1024)
        const int layer = id >> 8, h = id & 255;
        if (t < 32) {
            // per-n constants in double, once; broadcast via LDS
            const int n0 = t;
            const int idx = (layer * H + h) * N2 + n0;
            double dt = exp((double)log_dt[layer * H + h]);
            double Ar = -exp((double)log_Ar[idx]);
            double Ai = (double)A_im[idx];
            double dtr = dt * Ar, dti = dt * Ai;
            double er = exp(dtr);
            double dwr = er * cos(dti), dwi = er * sin(dti);
            double numr = dwr - 1.0, numi = dwi;
            double den = Ar * Ar + Ai * Ai;
            double qr0 = (numr * Ar + numi * Ai) / den;
            double qi0 = (numi * Ar - numr * Ai) / den;
            double dcr = (double)C_re[idx], dci = (double)C_im[idx];
            cS[n0]       = (float)(2.0 * (dcr * qr0 - dci * qi0));  // cr
            cS[32 + n0]  = (float)(2.0 * (dcr * qi0 + dci * qr0));  // ci
            cS[64 + n0]  = (float)dwr;                              // wr
            cS[96 + n0]  = (float)dwi;                              // wi
            double rev = dti * 0.15915494309189535;                 // dti/2pi
            cS[128 + n0] = (float)(rev - floor(rev));               // revf (frac)
            cS[160 + n0] = (float)dtr;                              // dtrf
            // w^64 in closed form (double): better than 64 serial f32 muls
            double m64 = exp(64.0 * dtr);
            double a64 = 64.0 * dti;
            w64c[(layer * H + h) * N2 + n0] =
                make_float2((float)(m64 * cos(a64)), (float)(m64 * sin(a64)));
        }
        __syncthreads();
        const int n = t & 31, dg = t >> 5;    // each thread: 8 d-values, one n
        const float cr = cS[n], ci = cS[32 + n];
        const float wr = cS[64 + n], wi = cS[96 + n];
        const float revf = cS[128 + n], dtrf = cS[160 + n];
#pragma unroll
        for (int i = 0; i < 8; ++i) {
            const int d = dg * 8 + i;
            // w^d = exp(d*dtr) * cis(2pi * frac(d*revf)) — no serial dependence
            float ph = (float)d * revf;
            ph = (ph - floorf(ph)) * 6.28318530718f;
            float mag = __expf((float)d * dtrf);
            float vr = mag * __cosf(ph);
            float vi = mag * __sinf(ph);
            float pk = fmaf(cr, vr, -(ci * vi));
            pk += __shfl_xor(pk, 1);  pk += __shfl_xor(pk, 2);
            pk += __shfl_xor(pk, 4);  pk += __shfl_xor(pk, 8);
            pk += __shfl_xor(pk, 16);
            if (n == 0) kbS[d] = pk;
            mmS[n * MJP + (63 - d)]        = f2bf(vr);
            mmS[(32 + n) * MJP + (63 - d)] = f2bf(vi);
            float v1r = vr * wr - vi * wi;            // w^{d+1}
            float v1i = vr * wi + vi * wr;
            tvS[d * TVP + 64 + n] = f2bf(fmaf(cr, v1r, -(ci * v1i)));
            tvS[d * TVP + 96 + n] = f2bf(-fmaf(cr, v1i, ci * v1r));
        }
        __syncthreads();
        {   // Toeplitz T fill: row r = t>>2, 16 cols -> two aligned short8 stores
            const int r = t >> 2, c0 = (t & 3) * 16;
            const float diag = kbS[0] + Dv[layer * H + h];
            short8 o8[2];
#pragma unroll
            for (int j = 0; j < 16; ++j) {
                int c = c0 + j;
                float val = (c > r) ? 0.f : ((c == r) ? diag : kbS[r - c]);
                o8[j >> 3][j & 7] = (short)f2bf(val);
            }
            *(short8*)&tvS[r * TVP + c0]     = o8[0];
            *(short8*)&tvS[r * TVP + c0 + 8] = o8[1];
        }
        __syncthreads();
        // coalesced blast-out (16 B/lane chunks)
        unsigned short* tv = TVc + (size_t)(layer * H + h) * BLK * TVP;
        unsigned short* mm = Mm + (size_t)(layer * H + h) * BLK * MJP;
        for (int c = t; c < (BLK * TVP) / 8; c += 256)
            *(short8*)(tv + c * 8) = *(const short8*)&tvS[c * 8];
        for (int c = t; c < (BLK * MJP) / 8; c += 256)
            *(short8*)(mm + c * 8) = *(const short8*)&mmS[c * 8];
    } else {
        // ---- transpose x (B,L,H) fp32 -> u (B,H,L) bf16 : 64l x 32h tiles, 4096 blocks ----
        float* sh = (float*)smem_raw;        // [32*68]
        const int rb = bid - 1536;           // [0, 4096)
        const int hx = rb & 7, ly = (rb >> 3) & 63, b = rb >> 9;
        const int h0 = hx * 32, l0 = ly * 64;
        const int tx = t & 7, ty = t >> 3;   // load: tx = h-quad (8x float4 = 32 h), ty = l-row (32)
        const float* xb = x + ((size_t)b * L + l0) * H + h0;
#pragma unroll
        for (int i = 0; i < 2; ++i) {
            int l = ty + i * 32;
            float4 v = *(const float4*)(xb + (size_t)l * H + tx * 4);
            sh[(tx * 4 + 0) * 68 + l] = v.x;
            sh[(tx * 4 + 1) * 68 + l] = v.y;
            sh[(tx * 4 + 2) * 68 + l] = v.z;
            sh[(tx * 4 + 3) * 68 + l] = v.w;
        }
        __syncthreads();
        // write: 32 h-rows x 64 u16 (128B contiguous per row)
        const int hh = t >> 3, cc = (t & 7) * 8;
        const float* row = &sh[hh * 68 + cc];
        short8 o8;
#pragma unroll
        for (int j = 0; j < 8; ++j) o8[j] = (short)f2bf(row[j]);
        *(short8*)(u + ((size_t)b * H + h0 + hh) * L + l0 + cc) = o8;
    }
}

// ---------------- fused scan: GEMM-A + 2-level chain + GEMM-B (row-ownership, round-8 layout) ----------------
__global__ __launch_bounds__(256) void k_scan3(
    const unsigned short* __restrict__ u, const unsigned short* __restrict__ Mm_l,
    const unsigned short* __restrict__ TVc_l, const float2* __restrict__ w64c_l,
    unsigned short* __restrict__ y)
{
    __shared__ __align__(16) unsigned short uT[BLK * UTP];   // 9.2 KB
    __shared__ __align__(16) unsigned short ST[BLK * UTP];   // 9.2 KB
    __shared__ __align__(16) float INC[BLK * INP];           // 17.4 KB
    __shared__ float2 cLd[4][32];
    const int t = threadIdx.x;
    const int wv = t >> 6, lane = t & 63;
    const int lanei = lane & 15, quad = lane >> 4;
    const int h = blockIdx.x >> 3, ct = blockIdx.x & 7;      // ct = batch
    const unsigned short* ub = u + (size_t)(ct * H + h) * L;

    // early register prefetch of all mats operands (hides L2/HBM latency under
    // staging + scan; hipcc won't hoist loads across __syncthreads)
    const unsigned short* arowA = Mm_l + (size_t)h * BLK * MJP + (wv * 16 + lanei) * MJP + quad * 8;
    short8 mA[2];
    mA[0] = *(const short8*)(arowA);
    mA[1] = *(const short8*)(arowA + 32);
    const unsigned short* arowB = TVc_l + (size_t)h * BLK * TVP + (wv * 16 + lanei) * TVP + quad * 8;
    short8 tB[4];
#pragma unroll
    for (int kt = 0; kt < 4; ++kt)
        tB[kt] = *(const short8*)(arowB + kt * 32);
    const float2 w64 = w64c_l[h * N2 + (lane & 31)];

    {   // stage uT[col=blk][j] bf16 (direct copy)
        int col = t >> 2, q = t & 3;
        *(short8*)&uT[col * UTP + q * 16]     = *(const short8*)(ub + col * 64 + q * 16);
        *(short8*)&uT[col * UTP + q * 16 + 8] = *(const short8*)(ub + col * 64 + q * 16 + 8);
    }
    __syncthreads();

    // ---- GEMM-A: INC[blk][k] = sum_j M[k][j] * u[blk*64+j] ----
    {
        f32x4 acc[4];
#pragma unroll
        for (int nt = 0; nt < 4; ++nt) acc[nt] = (f32x4){0.f, 0.f, 0.f, 0.f};
#pragma unroll
        for (int kt = 0; kt < 2; ++kt) {
#pragma unroll
            for (int nt = 0; nt < 4; ++nt) {
                short8 b8 = *(const short8*)&uT[(nt * 16 + lanei) * UTP + kt * 32 + quad * 8];
                acc[nt] = __builtin_amdgcn_mfma_f32_16x16x32_bf16(mA[kt], b8, acc[nt], 0, 0, 0);
            }
        }
#pragma unroll
        for (int nt = 0; nt < 4; ++nt)
            *(f32x4*)&INC[(nt * 16 + lanei) * INP + wv * 16 + quad * 4] = acc[nt];
    }
    __syncthreads();

    // ---- chain: two-level parallel scan (each wave owns 16 blocks) ----
    const int n = lane & 31;
    float Pr[16], Pi[16];
    float w1r = 1.f, w1i = 0.f;
    if (lane < 32) {
        float sr = 0.f, si = 0.f;
        const int base = wv * 16;
#pragma unroll
        for (int k = 0; k < 16; ++k) {
            Pr[k] = sr; Pi[k] = si;
            float ir = INC[(base + k) * INP + n];
            float ii = INC[(base + k) * INP + 32 + n];
            float nr = fmaf(w64.x, sr, fmaf(-w64.y, si, ir));
            float ni = fmaf(w64.x, si, fmaf(w64.y, sr, ii));
            sr = nr; si = ni;
        }
        cLd[wv][n] = make_float2(sr, si);
        float ar = w64.x, ai = w64.y;
#pragma unroll
        for (int q = 0; q < 4; ++q) {         // w64^16
            float nr2 = ar * ar - ai * ai;
            float ni2 = 2.f * ar * ai;
            ar = nr2; ai = ni2;
        }
        w1r = ar; w1i = ai;
    }
    __syncthreads();
    if (lane < 32) {
        float Cr = 0.f, Ci = 0.f;
        for (int wp = 0; wp < wv; ++wp) {
            float2 Lw = cLd[wp][n];
            float nr = fmaf(w1r, Cr, fmaf(-w1i, Ci, Lw.x));
            float ni = fmaf(w1r, Ci, fmaf(w1i, Cr, Lw.y));
            Cr = nr; Ci = ni;
        }
        float pr = 1.f, pi = 0.f;
#pragma unroll
        for (int k = 0; k < 16; ++k) {
            int blk = wv * 16 + k;
            float Sr = fmaf(pr, Cr, fmaf(-pi, Ci, Pr[k]));
            float Si = fmaf(pr, Ci, fmaf(pi, Cr, Pi[k]));
            ST[blk * UTP + n]      = f2bf(Sr);
            ST[blk * UTP + 32 + n] = f2bf(Si);
            float npr = pr * w64.x - pi * w64.y;
            float npi = pr * w64.y + pi * w64.x;
            pr = npr; pi = npi;
        }
    }
    __syncthreads();

    // ---- GEMM-B: y = gelu(T*U + Vc*S); restage via uT -> coalesced 16B stores ----
    {
        f32x4 acc[4];
#pragma unroll
        for (int nt = 0; nt < 4; ++nt) acc[nt] = (f32x4){0.f, 0.f, 0.f, 0.f};
#pragma unroll
        for (int kt = 0; kt < 4; ++kt) {
            const unsigned short* bb = (kt < 2) ? uT : ST;
            int ko = (kt & 1) * 32 + quad * 8;
#pragma unroll
            for (int nt = 0; nt < 4; ++nt) {
                short8 b8 = *(const short8*)&bb[(nt * 16 + lanei) * UTP + ko];
                acc[nt] = __builtin_amdgcn_mfma_f32_16x16x32_bf16(tB[kt], b8, acc[nt], 0, 0, 0);
            }
        }
        __syncthreads();   // all waves done reading uT -> safe to reuse
        // pack gelu(acc) into uT[blk][i] (the old direct ushort4 global store was a
        // 128B-strided 8B scatter: 64 cache lines per wave instruction)
#pragma unroll
        for (int nt = 0; nt < 4; ++nt) {
            int blk = nt * 16 + lanei;
            int i0 = wv * 16 + quad * 4;
            ushort4 o4;
            o4.x = f2bf(gelu_f(acc[nt][0]));
            o4.y = f2bf(gelu_f(acc[nt][1]));
            o4.z = f2bf(gelu_f(acc[nt][2]));
            o4.w = f2bf(gelu_f(acc[nt][3]));
            *(ushort4*)&uT[blk * UTP + i0] = o4;
        }
        __syncthreads();
        unsigned short* yb = y + (size_t)(ct * H + h) * L;
#pragma unroll
        for (int r = 0; r < 2; ++r) {
            int c = r * 256 + t;             // 512 chunks = 64 blk x 8
            int o = c >> 3, c8 = (c & 7) * 8;
            *(short8*)(yb + o * 64 + c8) = *(const short8*)&uT[o * UTP + c8];
        }
    }
}

// ---------------- MFMA GEMM(512x256 @ 256x32) + bias + GLU + residual(bf16) + channel-LN ----------------
// TL2=32, 256 threads (4 waves), 1024 blocks = 4 blocks/CU: 2x the independent
// barrier-groups per CU vs the old 512x512 config, and lower VGPR pressure.
__global__ __launch_bounds__(256, 4) void k_gemm(
    const unsigned short* __restrict__ y, unsigned short* __restrict__ u,
    const unsigned short* __restrict__ Wb, const float* __restrict__ bo,
    const float* __restrict__ lng, const float* __restrict__ lnb,
    float* __restrict__ outp)
{
    // yS lives: (1) y tile [TL2 rows x YPAD] for MFMA, (2) residual u tile
    // [256 rows x URP2], (3) LN-output restage. Sized for the max (10240 u16).
    __shared__ __align__(16) unsigned short yS[10240];        // 20.5 KB
    __shared__ float bS[O2];
    __shared__ float lgS[H], lbS[H];
    __shared__ float redS[4][2][16], redQ[4][2][16];

    const int t = threadIdx.x;
    const int wv = t >> 6;                   // 0..3
    const int lane = t & 63;
    const int lanei = lane & 15;
    const int quad = lane >> 4;
    const int b = blockIdx.x >> 7;           // L/TL2 = 128 tiles per batch
    const int l0 = (blockIdx.x & 127) * TL2;

    size_t abase[2][4];
#pragma unroll
    for (int p = 0; p < 2; ++p)
#pragma unroll
        for (int jj = 0; jj < 4; ++jj)
            abase[p][jj] = (size_t)(p * 256 + wv * 64 + jj * 16 + lanei) * H + quad * 8;

    {   // stage y tile (256h x 32l bf16) -> yS[l][h ^ 8*(l>>3)] (swizzled)
        const int i = t & 3, hr = t >> 2;    // i: l-octet 0..3, hr: 0..63
        const unsigned short* yb = y + (size_t)b * H * L + l0 + i * 8;
#pragma unroll
        for (int ps = 0; ps < 4; ++ps) {
            int h = ps * 64 + hr;
            short8 v8 = *(const short8*)(yb + (size_t)h * L);
#pragma unroll
            for (int r = 0; r < 8; ++r)
                yS[(i * 8 + r) * YPAD + (h ^ (8 * i))] = (unsigned short)v8[r];
        }
        bS[t] = bo[t];
        bS[t + 256] = bo[t + 256];
        lgS[t] = lng[t]; lbS[t] = lnb[t];
    }
    __syncthreads();

    f32x4 acc[2][4][2];
#pragma unroll
    for (int p = 0; p < 2; ++p)
#pragma unroll
        for (int jj = 0; jj < 4; ++jj)
#pragma unroll
            for (int nt = 0; nt < 2; ++nt)
                acc[p][jj][nt] = (f32x4){0.f, 0.f, 0.f, 0.f};

#pragma unroll
    for (int kt = 0; kt < 8; ++kt) {
        short8 bfr[2];
#pragma unroll
        for (int nt = 0; nt < 2; ++nt) {
            int lp = nt * 16 + lanei;
            int a = (2 * nt + (lanei >> 3)) & 7;
            bfr[nt] = *(const short8*)&yS[lp * YPAD + ((kt * 32 + quad * 8) ^ (8 * a))];
        }
#pragma unroll
        for (int p = 0; p < 2; ++p)
#pragma unroll
            for (int jj = 0; jj < 4; ++jj) {
                short8 a8 = *(const short8*)(Wb + abase[p][jj] + kt * 32);
#pragma unroll
                for (int nt = 0; nt < 2; ++nt)
                    acc[p][jj][nt] = __builtin_amdgcn_mfma_f32_16x16x32_bf16(
                        a8, bfr[nt], acc[p][jj][nt], 0, 0, 0);
            }
    }
    __syncthreads();   // all waves done reading yS -> safe to reuse

    // ---- stage residual u tile (256 x 32) into yS with coalesced short8 loads ----
    unsigned short* ub = u + (size_t)b * H * L + l0;
#pragma unroll
    for (int r = 0; r < 4; ++r) {
        int c = r * 256 + t;                 // 1024 chunks = 256 rows x 4
        int o = c >> 2, c8 = (c & 3) * 8;
        *(short8*)&yS[o * URP2 + c8] = *(const short8*)(ub + (size_t)o * L + c8);
    }
    __syncthreads();

    // ---- epilogue: bias + GLU + residual(from LDS); LN stats ----
    float psum[2] = {0.f, 0.f}, psq[2] = {0.f, 0.f};
#pragma unroll
    for (int jj = 0; jj < 4; ++jj) {
#pragma unroll
        for (int nt = 0; nt < 2; ++nt) {
            int lc = nt * 16 + lanei;
#pragma unroll
            for (int reg = 0; reg < 4; ++reg) {
                int o = wv * 64 + jj * 16 + quad * 4 + reg;
                float a = acc[0][jj][nt][reg] + bS[o];
                float g = acc[1][jj][nt][reg] + bS[o + 256];
                float glu = a / (1.f + __expf(-g));
                float val = glu + bf2f(yS[o * URP2 + lc]);
                acc[0][jj][nt][reg] = val;
                psum[nt] += val;
                psq[nt] = fmaf(val, val, psq[nt]);
            }
        }
    }
#pragma unroll
    for (int nt = 0; nt < 2; ++nt) {
        psum[nt] += __shfl_xor(psum[nt], 16);
        psum[nt] += __shfl_xor(psum[nt], 32);
        psq[nt]  += __shfl_xor(psq[nt], 16);
        psq[nt]  += __shfl_xor(psq[nt], 32);
    }
    if (lane < 16) {
#pragma unroll
        for (int nt = 0; nt < 2; ++nt) {
            redS[wv][nt][lanei] = psum[nt];
            redQ[wv][nt][lanei] = psq[nt];
        }
    }
    __syncthreads();   // also guarantees all residual reads of yS completed
    float mcol[2], icol[2];
#pragma unroll
    for (int nt = 0; nt < 2; ++nt) {
        float s = 0.f, q = 0.f;
#pragma unroll
        for (int w = 0; w < 4; ++w) { s += redS[w][nt][lanei]; q += redQ[w][nt][lanei]; }
        float m = s * (1.0f / 256.0f);
        float v = q * (1.0f / 256.0f) - m * m;
        mcol[nt] = m;
        icol[nt] = rsqrtf(v + 1e-5f);
    }
    if (outp == nullptr) {
        // restage LN output through yS, then coalesced short8 stores
#pragma unroll
        for (int jj = 0; jj < 4; ++jj) {
#pragma unroll
            for (int nt = 0; nt < 2; ++nt) {
                int lc = nt * 16 + lanei;
#pragma unroll
                for (int reg = 0; reg < 4; ++reg) {
                    int o = wv * 64 + jj * 16 + quad * 4 + reg;
                    float val = acc[0][jj][nt][reg];
                    float ov = (val - mcol[nt]) * icol[nt] * lgS[o] + lbS[o];
                    yS[o * URP2 + lc] = f2bf(ov);
                }
            }
        }
        __syncthreads();
#pragma unroll
        for (int r = 0; r < 4; ++r) {
            int c = r * 256 + t;
            int o = c >> 2, c8 = (c & 3) * 8;
            *(short8*)(ub + (size_t)o * L + c8) = *(const short8*)&yS[o * URP2 + c8];
        }
    } else {
        // final layer: write fp32 transposed out (B,L,H) directly
#pragma unroll
        for (int jj = 0; jj < 4; ++jj) {
#pragma unroll
            for (int nt = 0; nt < 2; ++nt) {
                int lc = nt * 16 + lanei;
                int o0 = wv * 64 + jj * 16 + quad * 4;
                float4 ov;
#pragma unroll
                for (int reg = 0; reg < 4; ++reg) {
                    int o = o0 + reg;
                    float val = acc[0][jj][nt][reg];
                    ((float*)&ov)[reg] = (val - mcol[nt]) * icol[nt] * lgS[o] + lbS[o];
                }
                *(float4*)(outp + ((size_t)b * L + l0 + lc) * H + o0) = ov;
            }
        }
    }
}

extern "C" void kernel_launch(void* const* d_in, const int* in_sizes, int n_in,
                              void* d_out, int out_size, void* d_ws, size_t ws_size,
                              hipStream_t stream)
{
    const float* x      = (const float*)d_in[0];
    const float* log_dt = (const float*)d_in[1];
    const float* log_Ar = (const float*)d_in[2];
    const float* A_im   = (const float*)d_in[3];
    const float* C_re   = (const float*)d_in[4];
    const float* C_im   = (const float*)d_in[5];
    const float* Dv     = (const float*)d_in[6];
    const float* Wout   = (const float*)d_in[7];
    const float* bout   = (const float*)d_in[8];
    const float* lng    = (const float*)d_in[9];
    const float* lnb    = (const float*)d_in[10];
    float* out = (float*)d_out;

    unsigned short* u   = (unsigned short*)d_ws;                          // 16.8 MB
    unsigned short* Wb  = u + (size_t)B * H * L;                          // 1 MB
    unsigned short* TVc = Wb + (size_t)NL * O2 * H;                       // 17.8 MB
    unsigned short* Mm  = TVc + (size_t)NL * H * BLK * TVP;               // 9.4 MB
    float2* w64c        = (float2*)(Mm + (size_t)NL * H * BLK * MJP);     // 0.26 MB
    unsigned short* y   = (unsigned short*)(w64c + (size_t)NL * H * N2);  // 16.8 MB

    // 512 wcvt + 1024 mats + 4096 tr_xu blocks
    k_setup<<<5632, 256, 0, stream>>>(x, log_dt, log_Ar, A_im, C_re, C_im, Dv, Wout,
                                      Wb, TVc, Mm, w64c, u);
    for (int layer = 0; layer < NL; ++layer) {
        k_scan3<<<H * 8, 256, 0, stream>>>(u, Mm + (size_t)layer * H * BLK * MJP,
                                           TVc + (size_t)layer * H * BLK * TVP,
                                           w64c + (size_t)layer * H * N2, y);
        k_gemm<<<B * L / TL2, 256, 0, stream>>>(y, u, Wb + (size_t)layer * O2 * H,
                                                bout + layer * O2, lng + layer * H, lnb + layer * H,
                                                (layer == NL - 1) ? out : nullptr);
    }
}

// Round 5
// 298.354 us; speedup vs baseline: 1.2090x; 1.2090x over previous
//
#include <hip/hip_runtime.h>
#include <math.h>

#define B    8
#define L    4096
#define H    256
#define N2   32
#define NL   4
#define O2   512   // 2H
#define BLK  64    // scan block length
#define NBLK 64    // L/BLK
#define TVP  136   // TVc row stride (elems): 64 T + 64 Vc + 8 pad
#define MJP  72    // Mm row stride
#define UTP  72    // uT/ST LDS row stride (u16), 144B = 16B-mult
#define INP  68    // INC LDS row stride (f32), 272B = 16B-mult
#define TL2  64    // k_gemm l-tile (measured best: 512-thread blocks, 34.5us; TL2=32 was 50us)
#define YPAD 264   // k_gemm yS row stride (u16)
#define URP  72    // k_gemm residual-tile LDS row stride (u16), 144B = 16B-mult

typedef __attribute__((ext_vector_type(8))) short short8;
typedef __attribute__((ext_vector_type(4))) float f32x4;

__device__ __forceinline__ unsigned short f2bf(float f)
{
    unsigned int u = __float_as_uint(f);
    unsigned int r = (u + 0x7fffu + ((u >> 16) & 1u)) >> 16;
    return (unsigned short)r;
}

__device__ __forceinline__ float bf2f(unsigned short v)
{
    return __uint_as_float(((unsigned int)v) << 16);
}

// fast GELU: x * sigmoid(1.5957691216(x + 0.044715 x^3)) — max err ~2e-3
__device__ __forceinline__ float gelu_f(float x)
{
    float t = 1.59576912161f * fmaf(0.044715f * x * x, x, x);
    return x / (1.f + __expf(-t));
}

// ---------------- merged setup: [0,512) wcvt | [512,1536) mats | [1536,5632) tr_xu ----------------
__global__ __launch_bounds__(256) void k_setup(
    const float* __restrict__ x, const float* __restrict__ log_dt,
    const float* __restrict__ log_Ar, const float* __restrict__ A_im,
    const float* __restrict__ C_re, const float* __restrict__ C_im,
    const float* __restrict__ Dv, const float* __restrict__ Wout,
    unsigned short* __restrict__ Wb, unsigned short* __restrict__ TVc,
    unsigned short* __restrict__ Mm, float2* __restrict__ w64c,
    unsigned short* __restrict__ u)
{
    // union: tr_xu uses 8.7 KB f32 tile; mats uses 27.6 KB staging
    __shared__ __align__(16) unsigned char smem_raw[27648];
    const int bid = blockIdx.x;
    const int t = threadIdx.x;

    if (bid < 512) {
        // ---- Wout fp32 -> bf16 ----
        int idx = (bid * 256 + t) * 4;
        float4 v = *(const float4*)(Wout + idx);
        ushort4 o;
        o.x = f2bf(v.x); o.y = f2bf(v.y); o.z = f2bf(v.z); o.w = f2bf(v.w);
        *(ushort4*)(Wb + idx) = o;
    } else if (bid < 1536) {
        // ---- build per-(layer,h): T|Vc, M, w^64 — one id per block ----
        unsigned short* tvS = (unsigned short*)smem_raw;      // [64*TVP] 17408 B
        unsigned short* mmS = tvS + BLK * TVP;                // [64*MJP]  9216 B
        float* kbS = (float*)(mmS + BLK * MJP);               // [64]       256 B
        float* cS  = kbS + BLK;                               // [6*32]     768 B
        const int id = bid - 512;                             // [0, 1024)
        const int layer = id >> 8, h = id & 255;
        if (t < 32) {
            // per-n constants in double, once; broadcast via LDS
            const int n0 = t;
            const int idx = (layer * H + h) * N2 + n0;
            double dt = exp((double)log_dt[layer * H + h]);
            double Ar = -exp((double)log_Ar[idx]);
            double Ai = (double)A_im[idx];
            double dtr = dt * Ar, dti = dt * Ai;
            double er = exp(dtr);
            double dwr = er * cos(dti), dwi = er * sin(dti);
            double numr = dwr - 1.0, numi = dwi;
            double den = Ar * Ar + Ai * Ai;
            double qr0 = (numr * Ar + numi * Ai) / den;
            double qi0 = (numi * Ar - numr * Ai) / den;
            double dcr = (double)C_re[idx], dci = (double)C_im[idx];
            cS[n0]       = (float)(2.0 * (dcr * qr0 - dci * qi0));  // cr
            cS[32 + n0]  = (float)(2.0 * (dcr * qi0 + dci * qr0));  // ci
            cS[64 + n0]  = (float)dwr;                              // wr
            cS[96 + n0]  = (float)dwi;                              // wi
            double rev = dti * 0.15915494309189535;                 // dti/2pi
            cS[128 + n0] = (float)(rev - floor(rev));               // revf (frac)
            cS[160 + n0] = (float)dtr;                              // dtrf
            // w^64 in closed form (double): better than 64 serial f32 muls
            double m64 = exp(64.0 * dtr);
            double a64 = 64.0 * dti;
            w64c[(layer * H + h) * N2 + n0] =
                make_float2((float)(m64 * cos(a64)), (float)(m64 * sin(a64)));
        }
        __syncthreads();
        const int n = t & 31, dg = t >> 5;    // each thread: 8 d-values, one n
        const float cr = cS[n], ci = cS[32 + n];
        const float wr = cS[64 + n], wi = cS[96 + n];
        const float revf = cS[128 + n], dtrf = cS[160 + n];
#pragma unroll
        for (int i = 0; i < 8; ++i) {
            const int d = dg * 8 + i;
            // w^d = exp(d*dtr) * cis(2pi * frac(d*revf)) — no serial dependence
            float ph = (float)d * revf;
            ph = (ph - floorf(ph)) * 6.28318530718f;
            float mag = __expf((float)d * dtrf);
            float vr = mag * __cosf(ph);
            float vi = mag * __sinf(ph);
            float pk = fmaf(cr, vr, -(ci * vi));
            pk += __shfl_xor(pk, 1);  pk += __shfl_xor(pk, 2);
            pk += __shfl_xor(pk, 4);  pk += __shfl_xor(pk, 8);
            pk += __shfl_xor(pk, 16);
            if (n == 0) kbS[d] = pk;
            mmS[n * MJP + (63 - d)]        = f2bf(vr);
            mmS[(32 + n) * MJP + (63 - d)] = f2bf(vi);
            float v1r = vr * wr - vi * wi;            // w^{d+1}
            float v1i = vr * wi + vi * wr;
            tvS[d * TVP + 64 + n] = f2bf(fmaf(cr, v1r, -(ci * v1i)));
            tvS[d * TVP + 96 + n] = f2bf(-fmaf(cr, v1i, ci * v1r));
        }
        __syncthreads();
        {   // Toeplitz T fill: row r = t>>2, 16 cols -> two aligned short8 stores
            const int r = t >> 2, c0 = (t & 3) * 16;
            const float diag = kbS[0] + Dv[layer * H + h];
            short8 o8[2];
#pragma unroll
            for (int j = 0; j < 16; ++j) {
                int c = c0 + j;
                float val = (c > r) ? 0.f : ((c == r) ? diag : kbS[r - c]);
                o8[j >> 3][j & 7] = (short)f2bf(val);
            }
            *(short8*)&tvS[r * TVP + c0]     = o8[0];
            *(short8*)&tvS[r * TVP + c0 + 8] = o8[1];
        }
        __syncthreads();
        // coalesced blast-out (16 B/lane chunks)
        unsigned short* tv = TVc + (size_t)(layer * H + h) * BLK * TVP;
        unsigned short* mm = Mm + (size_t)(layer * H + h) * BLK * MJP;
        for (int c = t; c < (BLK * TVP) / 8; c += 256)
            *(short8*)(tv + c * 8) = *(const short8*)&tvS[c * 8];
        for (int c = t; c < (BLK * MJP) / 8; c += 256)
            *(short8*)(mm + c * 8) = *(const short8*)&mmS[c * 8];
    } else {
        // ---- transpose x (B,L,H) fp32 -> u (B,H,L) bf16 : 64l x 32h tiles, 4096 blocks ----
        float* sh = (float*)smem_raw;        // [32*68]
        const int rb = bid - 1536;           // [0, 4096)
        const int hx = rb & 7, ly = (rb >> 3) & 63, b = rb >> 9;
        const int h0 = hx * 32, l0 = ly * 64;
        const int tx = t & 7, ty = t >> 3;   // load: tx = h-quad (8x float4 = 32 h), ty = l-row (32)
        const float* xb = x + ((size_t)b * L + l0) * H + h0;
#pragma unroll
        for (int i = 0; i < 2; ++i) {
            int l = ty + i * 32;
            float4 v = *(const float4*)(xb + (size_t)l * H + tx * 4);
            sh[(tx * 4 + 0) * 68 + l] = v.x;
            sh[(tx * 4 + 1) * 68 + l] = v.y;
            sh[(tx * 4 + 2) * 68 + l] = v.z;
            sh[(tx * 4 + 3) * 68 + l] = v.w;
        }
        __syncthreads();
        // write: 32 h-rows x 64 u16 (128B contiguous per row)
        const int hh = t >> 3, cc = (t & 7) * 8;
        const float* row = &sh[hh * 68 + cc];
        short8 o8;
#pragma unroll
        for (int j = 0; j < 8; ++j) o8[j] = (short)f2bf(row[j]);
        *(short8*)(u + ((size_t)b * H + h0 + hh) * L + l0 + cc) = o8;
    }
}

// ---------------- fused scan: GEMM-A + 2-level chain + GEMM-B (row-ownership, round-8 layout) ----------------
__global__ __launch_bounds__(256) void k_scan3(
    const unsigned short* __restrict__ u, const unsigned short* __restrict__ Mm_l,
    const unsigned short* __restrict__ TVc_l, const float2* __restrict__ w64c_l,
    unsigned short* __restrict__ y)
{
    __shared__ __align__(16) unsigned short uT[BLK * UTP];   // 9.2 KB
    __shared__ __align__(16) unsigned short ST[BLK * UTP];   // 9.2 KB
    __shared__ __align__(16) float INC[BLK * INP];           // 17.4 KB
    __shared__ float2 cLd[4][32];
    const int t = threadIdx.x;
    const int wv = t >> 6, lane = t & 63;
    const int lanei = lane & 15, quad = lane >> 4;
    const int h = blockIdx.x >> 3, ct = blockIdx.x & 7;      // ct = batch
    const unsigned short* ub = u + (size_t)(ct * H + h) * L;

    // early register prefetch of all mats operands (hides L2/HBM latency under
    // staging + scan; hipcc won't hoist loads across __syncthreads)
    const unsigned short* arowA = Mm_l + (size_t)h * BLK * MJP + (wv * 16 + lanei) * MJP + quad * 8;
    short8 mA[2];
    mA[0] = *(const short8*)(arowA);
    mA[1] = *(const short8*)(arowA + 32);
    const unsigned short* arowB = TVc_l + (size_t)h * BLK * TVP + (wv * 16 + lanei) * TVP + quad * 8;
    short8 tB[4];
#pragma unroll
    for (int kt = 0; kt < 4; ++kt)
        tB[kt] = *(const short8*)(arowB + kt * 32);
    const float2 w64 = w64c_l[h * N2 + (lane & 31)];

    {   // stage uT[col=blk][j] bf16 (direct copy)
        int col = t >> 2, q = t & 3;
        *(short8*)&uT[col * UTP + q * 16]     = *(const short8*)(ub + col * 64 + q * 16);
        *(short8*)&uT[col * UTP + q * 16 + 8] = *(const short8*)(ub + col * 64 + q * 16 + 8);
    }
    __syncthreads();

    // ---- GEMM-A: INC[blk][k] = sum_j M[k][j] * u[blk*64+j] ----
    {
        f32x4 acc[4];
#pragma unroll
        for (int nt = 0; nt < 4; ++nt) acc[nt] = (f32x4){0.f, 0.f, 0.f, 0.f};
#pragma unroll
        for (int kt = 0; kt < 2; ++kt) {
#pragma unroll
            for (int nt = 0; nt < 4; ++nt) {
                short8 b8 = *(const short8*)&uT[(nt * 16 + lanei) * UTP + kt * 32 + quad * 8];
                acc[nt] = __builtin_amdgcn_mfma_f32_16x16x32_bf16(mA[kt], b8, acc[nt], 0, 0, 0);
            }
        }
#pragma unroll
        for (int nt = 0; nt < 4; ++nt)
            *(f32x4*)&INC[(nt * 16 + lanei) * INP + wv * 16 + quad * 4] = acc[nt];
    }
    __syncthreads();

    // ---- chain: two-level parallel scan (each wave owns 16 blocks) ----
    const int n = lane & 31;
    float Pr[16], Pi[16];
    float w1r = 1.f, w1i = 0.f;
    if (lane < 32) {
        float sr = 0.f, si = 0.f;
        const int base = wv * 16;
#pragma unroll
        for (int k = 0; k < 16; ++k) {
            Pr[k] = sr; Pi[k] = si;
            float ir = INC[(base + k) * INP + n];
            float ii = INC[(base + k) * INP + 32 + n];
            float nr = fmaf(w64.x, sr, fmaf(-w64.y, si, ir));
            float ni = fmaf(w64.x, si, fmaf(w64.y, sr, ii));
            sr = nr; si = ni;
        }
        cLd[wv][n] = make_float2(sr, si);
        float ar = w64.x, ai = w64.y;
#pragma unroll
        for (int q = 0; q < 4; ++q) {         // w64^16
            float nr2 = ar * ar - ai * ai;
            float ni2 = 2.f * ar * ai;
            ar = nr2; ai = ni2;
        }
        w1r = ar; w1i = ai;
    }
    __syncthreads();
    if (lane < 32) {
        float Cr = 0.f, Ci = 0.f;
        for (int wp = 0; wp < wv; ++wp) {
            float2 Lw = cLd[wp][n];
            float nr = fmaf(w1r, Cr, fmaf(-w1i, Ci, Lw.x));
            float ni = fmaf(w1r, Ci, fmaf(w1i, Cr, Lw.y));
            Cr = nr; Ci = ni;
        }
        float pr = 1.f, pi = 0.f;
#pragma unroll
        for (int k = 0; k < 16; ++k) {
            int blk = wv * 16 + k;
            float Sr = fmaf(pr, Cr, fmaf(-pi, Ci, Pr[k]));
            float Si = fmaf(pr, Ci, fmaf(pi, Cr, Pi[k]));
            ST[blk * UTP + n]      = f2bf(Sr);
            ST[blk * UTP + 32 + n] = f2bf(Si);
            float npr = pr * w64.x - pi * w64.y;
            float npi = pr * w64.y + pi * w64.x;
            pr = npr; pi = npi;
        }
    }
    __syncthreads();

    // ---- GEMM-B: y = gelu(T*U + Vc*S); restage via uT -> coalesced 16B stores ----
    {
        f32x4 acc[4];
#pragma unroll
        for (int nt = 0; nt < 4; ++nt) acc[nt] = (f32x4){0.f, 0.f, 0.f, 0.f};
#pragma unroll
        for (int kt = 0; kt < 4; ++kt) {
            const unsigned short* bb = (kt < 2) ? uT : ST;
            int ko = (kt & 1) * 32 + quad * 8;
#pragma unroll
            for (int nt = 0; nt < 4; ++nt) {
                short8 b8 = *(const short8*)&bb[(nt * 16 + lanei) * UTP + ko];
                acc[nt] = __builtin_amdgcn_mfma_f32_16x16x32_bf16(tB[kt], b8, acc[nt], 0, 0, 0);
            }
        }
        __syncthreads();   // all waves done reading uT -> safe to reuse
        // pack gelu(acc) into uT[blk][i] (direct ushort4 global store was a
        // 128B-strided 8B scatter: 64 cache lines per wave instruction)
#pragma unroll
        for (int nt = 0; nt < 4; ++nt) {
            int blk = nt * 16 + lanei;
            int i0 = wv * 16 + quad * 4;
            ushort4 o4;
            o4.x = f2bf(gelu_f(acc[nt][0]));
            o4.y = f2bf(gelu_f(acc[nt][1]));
            o4.z = f2bf(gelu_f(acc[nt][2]));
            o4.w = f2bf(gelu_f(acc[nt][3]));
            *(ushort4*)&uT[blk * UTP + i0] = o4;
        }
        __syncthreads();
        unsigned short* yb = y + (size_t)(ct * H + h) * L;
#pragma unroll
        for (int r = 0; r < 2; ++r) {
            int c = r * 256 + t;             // 512 chunks = 64 blk x 8
            int o = c >> 3, c8 = (c & 7) * 8;
            *(short8*)(yb + o * 64 + c8) = *(const short8*)&uT[o * UTP + c8];
        }
    }
}

// ---------------- MFMA GEMM(512x256 @ 256x64) + bias + GLU + residual(bf16) + channel-LN ----------------
// 512 threads, TL2=64 (measured 34.5us; TL2=32/256thr was 50us: per-thread W-load
// chain doubled and L2 latency serially exposed). W fragments for each kt loaded
// as a BATCH of 4 (4-deep MLP on the L2 chain) instead of load->4xMFMA->load.
__global__ __launch_bounds__(512, 4) void k_gemm(
    const unsigned short* __restrict__ y, unsigned short* __restrict__ u,
    const unsigned short* __restrict__ Wb, const float* __restrict__ bo,
    const float* __restrict__ lng, const float* __restrict__ lnb,
    float* __restrict__ outp)
{
    // yS lives: (1) y tile for MFMA [TL2*YPAD], (2) residual u tile [H x URP],
    // (3) LN-output restage. Sized for the max of the three.
    __shared__ __align__(16) unsigned short yS[H * URP];      // 36.9 KB
    __shared__ float bS[O2];
    __shared__ float lgS[H], lbS[H];
    __shared__ float redS[8][4][16], redQ[8][4][16];

    const int t = threadIdx.x;
    const int wv = t >> 6;
    const int lane = t & 63;
    const int lanei = lane & 15;
    const int quad = lane >> 4;
    const int b = blockIdx.x >> 6;           // L/TL2 = 64 tiles per batch
    const int l0 = (blockIdx.x & 63) * TL2;

    size_t abase[2][2];
#pragma unroll
    for (int p = 0; p < 2; ++p)
#pragma unroll
        for (int jj = 0; jj < 2; ++jj)
            abase[p][jj] = (size_t)(p * 256 + wv * 32 + jj * 16 + lanei) * H + quad * 8;

    // kt=0 W fragments issued before the barrier: pre-barrier vmcnt drain hides their L2 latency
    short8 a8p[4];
#pragma unroll
    for (int p = 0; p < 2; ++p)
#pragma unroll
        for (int jj = 0; jj < 2; ++jj)
            a8p[p * 2 + jj] = *(const short8*)(Wb + abase[p][jj]);

    {   // stage y tile (256h x 64l bf16) -> yS[l][h ^ 8*(l>>3)] (swizzled)
        const int i = t & 7, hr = t >> 3;    // i: l-octet 0..7, hr: 0..63
        const unsigned short* yb = y + (size_t)b * H * L + l0 + i * 8;
#pragma unroll
        for (int ps = 0; ps < 4; ++ps) {
            int h = ps * 64 + hr;
            short8 v8 = *(const short8*)(yb + (size_t)h * L);
#pragma unroll
            for (int r = 0; r < 8; ++r)
                yS[(i * 8 + r) * YPAD + (h ^ (8 * i))] = (unsigned short)v8[r];
        }
        if (t < O2) bS[t] = bo[t];
        if (t < H) { lgS[t] = lng[t]; lbS[t] = lnb[t]; }
    }
    __syncthreads();

    f32x4 acc[2][2][4];
#pragma unroll
    for (int p = 0; p < 2; ++p)
#pragma unroll
        for (int jj = 0; jj < 2; ++jj)
#pragma unroll
            for (int nt = 0; nt < 4; ++nt)
                acc[p][jj][nt] = (f32x4){0.f, 0.f, 0.f, 0.f};

#pragma unroll
    for (int kt = 0; kt < 8; ++kt) {
        // batch the 4 W-fragment loads of this kt: 4 L2 requests in flight
        // together instead of serialized load->MFMA->load chains
        short8 a8[4];
        if (kt == 0) {
            a8[0] = a8p[0]; a8[1] = a8p[1]; a8[2] = a8p[2]; a8[3] = a8p[3];
        } else {
#pragma unroll
            for (int q = 0; q < 4; ++q)
                a8[q] = *(const short8*)(Wb + abase[q >> 1][q & 1] + kt * 32);
        }
        short8 bfr[4];
#pragma unroll
        for (int nt = 0; nt < 4; ++nt) {
            int lp = nt * 16 + lanei;
            int a = (2 * nt + (lanei >> 3)) & 7;
            bfr[nt] = *(const short8*)&yS[lp * YPAD + ((kt * 32 + quad * 8) ^ (8 * a))];
        }
#pragma unroll
        for (int p = 0; p < 2; ++p)
#pragma unroll
            for (int jj = 0; jj < 2; ++jj) {
#pragma unroll
                for (int nt = 0; nt < 4; ++nt)
                    acc[p][jj][nt] = __builtin_amdgcn_mfma_f32_16x16x32_bf16(
                        a8[p * 2 + jj], bfr[nt], acc[p][jj][nt], 0, 0, 0);
            }
    }
    __syncthreads();   // all waves done reading yS -> safe to reuse

    // ---- stage residual u tile into yS with coalesced short8 loads ----
    unsigned short* ub = u + (size_t)b * H * L + l0;
#pragma unroll
    for (int r = 0; r < 4; ++r) {
        int c = r * 512 + t;                 // 2048 chunks = 256 rows x 8
        int o = c >> 3, c8 = (c & 7) * 8;
        *(short8*)&yS[o * URP + c8] = *(const short8*)(ub + (size_t)o * L + c8);
    }
    __syncthreads();

    // ---- epilogue: bias + GLU + residual(from LDS); LN stats ----
    float psum[4] = {0.f, 0.f, 0.f, 0.f}, psq[4] = {0.f, 0.f, 0.f, 0.f};
#pragma unroll
    for (int jj = 0; jj < 2; ++jj) {
#pragma unroll
        for (int nt = 0; nt < 4; ++nt) {
            int lc = nt * 16 + lanei;
#pragma unroll
            for (int reg = 0; reg < 4; ++reg) {
                int o = wv * 32 + jj * 16 + quad * 4 + reg;
                float a = acc[0][jj][nt][reg] + bS[o];
                float g = acc[1][jj][nt][reg] + bS[o + 256];
                float glu = a / (1.f + __expf(-g));
                float val = glu + bf2f(yS[o * URP + lc]);
                acc[0][jj][nt][reg] = val;
                psum[nt] += val;
                psq[nt] = fmaf(val, val, psq[nt]);
            }
        }
    }
#pragma unroll
    for (int nt = 0; nt < 4; ++nt) {
        psum[nt] += __shfl_xor(psum[nt], 16);
        psum[nt] += __shfl_xor(psum[nt], 32);
        psq[nt]  += __shfl_xor(psq[nt], 16);
        psq[nt]  += __shfl_xor(psq[nt], 32);
    }
    if (lane < 16) {
#pragma unroll
        for (int nt = 0; nt < 4; ++nt) {
            redS[wv][nt][lanei] = psum[nt];
            redQ[wv][nt][lanei] = psq[nt];
        }
    }
    __syncthreads();   // also guarantees all residual reads of yS completed
    float mcol[4], icol[4];
#pragma unroll
    for (int nt = 0; nt < 4; ++nt) {
        float s = 0.f, q = 0.f;
#pragma unroll
        for (int w = 0; w < 8; ++w) { s += redS[w][nt][lanei]; q += redQ[w][nt][lanei]; }
        float m = s * (1.0f / 256.0f);
        float v = q * (1.0f / 256.0f) - m * m;
        mcol[nt] = m;
        icol[nt] = rsqrtf(v + 1e-5f);
    }
    if (outp == nullptr) {
        // restage LN output through yS, then coalesced short8 stores
#pragma unroll
        for (int jj = 0; jj < 2; ++jj) {
#pragma unroll
            for (int nt = 0; nt < 4; ++nt) {
                int lc = nt * 16 + lanei;
#pragma unroll
                for (int reg = 0; reg < 4; ++reg) {
                    int o = wv * 32 + jj * 16 + quad * 4 + reg;
                    float val = acc[0][jj][nt][reg];
                    float ov = (val - mcol[nt]) * icol[nt] * lgS[o] + lbS[o];
                    yS[o * URP + lc] = f2bf(ov);
                }
            }
        }
        __syncthreads();
#pragma unroll
        for (int r = 0; r < 4; ++r) {
            int c = r * 512 + t;
            int o = c >> 3, c8 = (c & 7) * 8;
            *(short8*)(ub + (size_t)o * L + c8) = *(const short8*)&yS[o * URP + c8];
        }
    } else {
        // final layer: write fp32 transposed out (B,L,H) directly
#pragma unroll
        for (int jj = 0; jj < 2; ++jj) {
#pragma unroll
            for (int nt = 0; nt < 4; ++nt) {
                int lc = nt * 16 + lanei;
                int o0 = wv * 32 + jj * 16 + quad * 4;
                float4 ov;
#pragma unroll
                for (int reg = 0; reg < 4; ++reg) {
                    int o = o0 + reg;
                    float val = acc[0][jj][nt][reg];
                    ((float*)&ov)[reg] = (val - mcol[nt]) * icol[nt] * lgS[o] + lbS[o];
                }
                *(float4*)(outp + ((size_t)b * L + l0 + lc) * H + o0) = ov;
            }
        }
    }
}

extern "C" void kernel_launch(void* const* d_in, const int* in_sizes, int n_in,
                              void* d_out, int out_size, void* d_ws, size_t ws_size,
                              hipStream_t stream)
{
    const float* x      = (const float*)d_in[0];
    const float* log_dt = (const float*)d_in[1];
    const float* log_Ar = (const float*)d_in[2];
    const float* A_im   = (const float*)d_in[3];
    const float* C_re   = (const float*)d_in[4];
    const float* C_im   = (const float*)d_in[5];
    const float* Dv     = (const float*)d_in[6];
    const float* Wout   = (const float*)d_in[7];
    const float* bout   = (const float*)d_in[8];
    const float* lng    = (const float*)d_in[9];
    const float* lnb    = (const float*)d_in[10];
    float* out = (float*)d_out;

    unsigned short* u   = (unsigned short*)d_ws;                          // 16.8 MB
    unsigned short* Wb  = u + (size_t)B * H * L;                          // 1 MB
    unsigned short* TVc = Wb + (size_t)NL * O2 * H;                       // 17.8 MB
    unsigned short* Mm  = TVc + (size_t)NL * H * BLK * TVP;               // 9.4 MB
    float2* w64c        = (float2*)(Mm + (size_t)NL * H * BLK * MJP);     // 0.26 MB
    unsigned short* y   = (unsigned short*)(w64c + (size_t)NL * H * N2);  // 16.8 MB

    // 512 wcvt + 1024 mats + 4096 tr_xu blocks
    k_setup<<<5632, 256, 0, stream>>>(x, log_dt, log_Ar, A_im, C_re, C_im, Dv, Wout,
                                      Wb, TVc, Mm, w64c, u);
    for (int layer = 0; layer < NL; ++layer) {
        k_scan3<<<H * 8, 256, 0, stream>>>(u, Mm + (size_t)layer * H * BLK * MJP,
                                           TVc + (size_t)layer * H * BLK * TVP,
                                           w64c + (size_t)layer * H * N2, y);
        k_gemm<<<B * L / TL2, 512, 0, stream>>>(y, u, Wb + (size_t)layer * O2 * H,
                                                bout + layer * O2, lng + layer * H, lnb + layer * H,
                                                (layer == NL - 1) ? out : nullptr);
    }
}

// Round 6
// 294.827 us; speedup vs baseline: 1.2235x; 1.0120x over previous
//
#include <hip/hip_runtime.h>
#include <math.h>

#define B    8
#define L    4096
#define H    256
#define N2   32
#define NL   4
#define O2   512   // 2H
#define BLK  64    // scan block length
#define NBLK 64    // L/BLK
#define TVP  136   // TVc row stride (elems): 64 T + 64 Vc + 8 pad
#define MJP  72    // Mm row stride
#define UTP  72    // uT/ST LDS row stride (u16), 144B = 16B-mult
#define INP  68    // INC LDS row stride (f32), 272B = 16B-mult
#define TL2  64    // k_gemm l-tile (measured best: 512-thread blocks; TL2=32 was 50us)
#define YPAD 264   // k_gemm yS row stride (u16)
#define URP  72    // k_gemm residual-tile LDS row stride (u16), 144B = 16B-mult

typedef __attribute__((ext_vector_type(8))) short short8;
typedef __attribute__((ext_vector_type(4))) float f32x4;

__device__ __forceinline__ unsigned short f2bf(float f)
{
    unsigned int u = __float_as_uint(f);
    unsigned int r = (u + 0x7fffu + ((u >> 16) & 1u)) >> 16;
    return (unsigned short)r;
}

__device__ __forceinline__ float bf2f(unsigned short v)
{
    return __uint_as_float(((unsigned int)v) << 16);
}

// fast GELU: x * sigmoid(1.5957691216(x + 0.044715 x^3)) — max err ~2e-3
__device__ __forceinline__ float gelu_f(float x)
{
    float t = 1.59576912161f * fmaf(0.044715f * x * x, x, x);
    return x / (1.f + __expf(-t));
}

// ---------------- merged setup: [0,512) wcvt | [512,1536) mats | [1536,5632) tr_xu ----------------
__global__ __launch_bounds__(256) void k_setup(
    const float* __restrict__ x, const float* __restrict__ log_dt,
    const float* __restrict__ log_Ar, const float* __restrict__ A_im,
    const float* __restrict__ C_re, const float* __restrict__ C_im,
    const float* __restrict__ Dv, const float* __restrict__ Wout,
    unsigned short* __restrict__ Wb, unsigned short* __restrict__ TVc,
    unsigned short* __restrict__ Mm, float2* __restrict__ w64c,
    unsigned short* __restrict__ u)
{
    // union: tr_xu uses 8.7 KB f32 tile; mats uses 27.6 KB staging
    __shared__ __align__(16) unsigned char smem_raw[27648];
    const int bid = blockIdx.x;
    const int t = threadIdx.x;

    if (bid < 512) {
        // ---- Wout fp32 -> bf16 ----
        int idx = (bid * 256 + t) * 4;
        float4 v = *(const float4*)(Wout + idx);
        ushort4 o;
        o.x = f2bf(v.x); o.y = f2bf(v.y); o.z = f2bf(v.z); o.w = f2bf(v.w);
        *(ushort4*)(Wb + idx) = o;
    } else if (bid < 1536) {
        // ---- build per-(layer,h): T|Vc, M, w^64 — one id per block ----
        unsigned short* tvS = (unsigned short*)smem_raw;      // [64*TVP] 17408 B
        unsigned short* mmS = tvS + BLK * TVP;                // [64*MJP]  9216 B
        float* kbS = (float*)(mmS + BLK * MJP);               // [64]       256 B
        float* cS  = kbS + BLK;                               // [6*32]     768 B
        const int id = bid - 512;                             // [0, 1024)
        const int layer = id >> 8, h = id & 255;
        if (t < 32) {
            // per-n constants in double, once; broadcast via LDS
            const int n0 = t;
            const int idx = (layer * H + h) * N2 + n0;
            double dt = exp((double)log_dt[layer * H + h]);
            double Ar = -exp((double)log_Ar[idx]);
            double Ai = (double)A_im[idx];
            double dtr = dt * Ar, dti = dt * Ai;
            double er = exp(dtr);
            double dwr = er * cos(dti), dwi = er * sin(dti);
            double numr = dwr - 1.0, numi = dwi;
            double den = Ar * Ar + Ai * Ai;
            double qr0 = (numr * Ar + numi * Ai) / den;
            double qi0 = (numi * Ar - numr * Ai) / den;
            double dcr = (double)C_re[idx], dci = (double)C_im[idx];
            cS[n0]       = (float)(2.0 * (dcr * qr0 - dci * qi0));  // cr
            cS[32 + n0]  = (float)(2.0 * (dcr * qi0 + dci * qr0));  // ci
            cS[64 + n0]  = (float)dwr;                              // wr
            cS[96 + n0]  = (float)dwi;                              // wi
            double rev = dti * 0.15915494309189535;                 // dti/2pi
            cS[128 + n0] = (float)(rev - floor(rev));               // revf (frac)
            cS[160 + n0] = (float)dtr;                              // dtrf
            // w^64 in closed form (double): better than 64 serial f32 muls
            double m64 = exp(64.0 * dtr);
            double a64 = 64.0 * dti;
            w64c[(layer * H + h) * N2 + n0] =
                make_float2((float)(m64 * cos(a64)), (float)(m64 * sin(a64)));
        }
        __syncthreads();
        const int n = t & 31, dg = t >> 5;    // each thread: 8 d-values, one n
        const float cr = cS[n], ci = cS[32 + n];
        const float wr = cS[64 + n], wi = cS[96 + n];
        const float revf = cS[128 + n], dtrf = cS[160 + n];
#pragma unroll
        for (int i = 0; i < 8; ++i) {
            const int d = dg * 8 + i;
            // w^d = exp(d*dtr) * cis(2pi * frac(d*revf)) — no serial dependence
            float ph = (float)d * revf;
            ph = (ph - floorf(ph)) * 6.28318530718f;
            float mag = __expf((float)d * dtrf);
            float vr = mag * __cosf(ph);
            float vi = mag * __sinf(ph);
            float pk = fmaf(cr, vr, -(ci * vi));
            pk += __shfl_xor(pk, 1);  pk += __shfl_xor(pk, 2);
            pk += __shfl_xor(pk, 4);  pk += __shfl_xor(pk, 8);
            pk += __shfl_xor(pk, 16);
            if (n == 0) kbS[d] = pk;
            mmS[n * MJP + (63 - d)]        = f2bf(vr);
            mmS[(32 + n) * MJP + (63 - d)] = f2bf(vi);
            float v1r = vr * wr - vi * wi;            // w^{d+1}
            float v1i = vr * wi + vi * wr;
            tvS[d * TVP + 64 + n] = f2bf(fmaf(cr, v1r, -(ci * v1i)));
            tvS[d * TVP + 96 + n] = f2bf(-fmaf(cr, v1i, ci * v1r));
        }
        __syncthreads();
        {   // Toeplitz T fill: row r = t>>2, 16 cols -> two aligned short8 stores
            const int r = t >> 2, c0 = (t & 3) * 16;
            const float diag = kbS[0] + Dv[layer * H + h];
            short8 o8[2];
#pragma unroll
            for (int j = 0; j < 16; ++j) {
                int c = c0 + j;
                float val = (c > r) ? 0.f : ((c == r) ? diag : kbS[r - c]);
                o8[j >> 3][j & 7] = (short)f2bf(val);
            }
            *(short8*)&tvS[r * TVP + c0]     = o8[0];
            *(short8*)&tvS[r * TVP + c0 + 8] = o8[1];
        }
        __syncthreads();
        // coalesced blast-out (16 B/lane chunks)
        unsigned short* tv = TVc + (size_t)(layer * H + h) * BLK * TVP;
        unsigned short* mm = Mm + (size_t)(layer * H + h) * BLK * MJP;
        for (int c = t; c < (BLK * TVP) / 8; c += 256)
            *(short8*)(tv + c * 8) = *(const short8*)&tvS[c * 8];
        for (int c = t; c < (BLK * MJP) / 8; c += 256)
            *(short8*)(mm + c * 8) = *(const short8*)&mmS[c * 8];
    } else {
        // ---- transpose x (B,L,H) fp32 -> u (B,H,L) bf16 : 64l x 32h tiles, 4096 blocks ----
        float* sh = (float*)smem_raw;        // [32*68]
        const int rb = bid - 1536;           // [0, 4096)
        const int hx = rb & 7, ly = (rb >> 3) & 63, b = rb >> 9;
        const int h0 = hx * 32, l0 = ly * 64;
        const int tx = t & 7, ty = t >> 3;   // load: tx = h-quad (8x float4 = 32 h), ty = l-row (32)
        const float* xb = x + ((size_t)b * L + l0) * H + h0;
#pragma unroll
        for (int i = 0; i < 2; ++i) {
            int l = ty + i * 32;
            float4 v = *(const float4*)(xb + (size_t)l * H + tx * 4);
            sh[(tx * 4 + 0) * 68 + l] = v.x;
            sh[(tx * 4 + 1) * 68 + l] = v.y;
            sh[(tx * 4 + 2) * 68 + l] = v.z;
            sh[(tx * 4 + 3) * 68 + l] = v.w;
        }
        __syncthreads();
        // write: 32 h-rows x 64 u16 (128B contiguous per row)
        const int hh = t >> 3, cc = (t & 7) * 8;
        const float* row = &sh[hh * 68 + cc];
        short8 o8;
#pragma unroll
        for (int j = 0; j < 8; ++j) o8[j] = (short)f2bf(row[j]);
        *(short8*)(u + ((size_t)b * H + h0 + hh) * L + l0 + cc) = o8;
    }
}

// ---------------- fused scan: GEMM-A + 2-level chain + GEMM-B (row-ownership, round-8 layout) ----------------
__global__ __launch_bounds__(256) void k_scan3(
    const unsigned short* __restrict__ u, const unsigned short* __restrict__ Mm_l,
    const unsigned short* __restrict__ TVc_l, const float2* __restrict__ w64c_l,
    unsigned short* __restrict__ y)
{
    __shared__ __align__(16) unsigned short uT[BLK * UTP];   // 9.2 KB
    __shared__ __align__(16) unsigned short ST[BLK * UTP];   // 9.2 KB
    __shared__ __align__(16) float INC[BLK * INP];           // 17.4 KB
    __shared__ float2 cLd[4][32];
    const int t = threadIdx.x;
    const int wv = t >> 6, lane = t & 63;
    const int lanei = lane & 15, quad = lane >> 4;
    // XCD-sharing decomposition: h = bid&255 makes the 8 batch-siblings that
    // read the SAME Mm[h]/TVc[h] (27 KB) land on the same XCD residue
    // (bid mod 8 identical since 256%8==0) -> mats fetched from HBM once per
    // XCD group instead of 8x. Old (h=bid>>3, ct=bid&7) put siblings on 8
    // DIFFERENT XCDs: ~48 MB/layer redundant HBM traffic.
    const int h = blockIdx.x & 255, ct = blockIdx.x >> 8;    // ct = batch
    const unsigned short* ub = u + (size_t)(ct * H + h) * L;

    // early register prefetch of all mats operands (hides L2/HBM latency under
    // staging + scan; hipcc won't hoist loads across __syncthreads)
    const unsigned short* arowA = Mm_l + (size_t)h * BLK * MJP + (wv * 16 + lanei) * MJP + quad * 8;
    short8 mA[2];
    mA[0] = *(const short8*)(arowA);
    mA[1] = *(const short8*)(arowA + 32);
    const unsigned short* arowB = TVc_l + (size_t)h * BLK * TVP + (wv * 16 + lanei) * TVP + quad * 8;
    short8 tB[4];
#pragma unroll
    for (int kt = 0; kt < 4; ++kt)
        tB[kt] = *(const short8*)(arowB + kt * 32);
    const float2 w64 = w64c_l[h * N2 + (lane & 31)];

    {   // stage uT[col=blk][j] bf16 (direct copy)
        int col = t >> 2, q = t & 3;
        *(short8*)&uT[col * UTP + q * 16]     = *(const short8*)(ub + col * 64 + q * 16);
        *(short8*)&uT[col * UTP + q * 16 + 8] = *(const short8*)(ub + col * 64 + q * 16 + 8);
    }
    __syncthreads();

    // ---- GEMM-A: INC[blk][k] = sum_j M[k][j] * u[blk*64+j] ----
    {
        f32x4 acc[4];
#pragma unroll
        for (int nt = 0; nt < 4; ++nt) acc[nt] = (f32x4){0.f, 0.f, 0.f, 0.f};
#pragma unroll
        for (int kt = 0; kt < 2; ++kt) {
#pragma unroll
            for (int nt = 0; nt < 4; ++nt) {
                short8 b8 = *(const short8*)&uT[(nt * 16 + lanei) * UTP + kt * 32 + quad * 8];
                acc[nt] = __builtin_amdgcn_mfma_f32_16x16x32_bf16(mA[kt], b8, acc[nt], 0, 0, 0);
            }
        }
#pragma unroll
        for (int nt = 0; nt < 4; ++nt)
            *(f32x4*)&INC[(nt * 16 + lanei) * INP + wv * 16 + quad * 4] = acc[nt];
    }
    __syncthreads();

    // ---- chain: two-level parallel scan (each wave owns 16 blocks) ----
    const int n = lane & 31;
    float Pr[16], Pi[16];
    float w1r = 1.f, w1i = 0.f;
    if (lane < 32) {
        float sr = 0.f, si = 0.f;
        const int base = wv * 16;
#pragma unroll
        for (int k = 0; k < 16; ++k) {
            Pr[k] = sr; Pi[k] = si;
            float ir = INC[(base + k) * INP + n];
            float ii = INC[(base + k) * INP + 32 + n];
            float nr = fmaf(w64.x, sr, fmaf(-w64.y, si, ir));
            float ni = fmaf(w64.x, si, fmaf(w64.y, sr, ii));
            sr = nr; si = ni;
        }
        cLd[wv][n] = make_float2(sr, si);
        float ar = w64.x, ai = w64.y;
#pragma unroll
        for (int q = 0; q < 4; ++q) {         // w64^16
            float nr2 = ar * ar - ai * ai;
            float ni2 = 2.f * ar * ai;
            ar = nr2; ai = ni2;
        }
        w1r = ar; w1i = ai;
    }
    __syncthreads();
    if (lane < 32) {
        float Cr = 0.f, Ci = 0.f;
        for (int wp = 0; wp < wv; ++wp) {
            float2 Lw = cLd[wp][n];
            float nr = fmaf(w1r, Cr, fmaf(-w1i, Ci, Lw.x));
            float ni = fmaf(w1r, Ci, fmaf(w1i, Cr, Lw.y));
            Cr = nr; Ci = ni;
        }
        float pr = 1.f, pi = 0.f;
#pragma unroll
        for (int k = 0; k < 16; ++k) {
            int blk = wv * 16 + k;
            float Sr = fmaf(pr, Cr, fmaf(-pi, Ci, Pr[k]));
            float Si = fmaf(pr, Ci, fmaf(pi, Cr, Pi[k]));
            ST[blk * UTP + n]      = f2bf(Sr);
            ST[blk * UTP + 32 + n] = f2bf(Si);
            float npr = pr * w64.x - pi * w64.y;
            float npi = pr * w64.y + pi * w64.x;
            pr = npr; pi = npi;
        }
    }
    __syncthreads();

    // ---- GEMM-B: y = gelu(T*U + Vc*S); restage via uT -> coalesced 16B stores ----
    {
        f32x4 acc[4];
#pragma unroll
        for (int nt = 0; nt < 4; ++nt) acc[nt] = (f32x4){0.f, 0.f, 0.f, 0.f};
#pragma unroll
        for (int kt = 0; kt < 4; ++kt) {
            const unsigned short* bb = (kt < 2) ? uT : ST;
            int ko = (kt & 1) * 32 + quad * 8;
#pragma unroll
            for (int nt = 0; nt < 4; ++nt) {
                short8 b8 = *(const short8*)&bb[(nt * 16 + lanei) * UTP + ko];
                acc[nt] = __builtin_amdgcn_mfma_f32_16x16x32_bf16(tB[kt], b8, acc[nt], 0, 0, 0);
            }
        }
        __syncthreads();   // all waves done reading uT -> safe to reuse
        // pack gelu(acc) into uT[blk][i] (direct ushort4 global store was a
        // 128B-strided 8B scatter: 64 cache lines per wave instruction)
#pragma unroll
        for (int nt = 0; nt < 4; ++nt) {
            int blk = nt * 16 + lanei;
            int i0 = wv * 16 + quad * 4;
            ushort4 o4;
            o4.x = f2bf(gelu_f(acc[nt][0]));
            o4.y = f2bf(gelu_f(acc[nt][1]));
            o4.z = f2bf(gelu_f(acc[nt][2]));
            o4.w = f2bf(gelu_f(acc[nt][3]));
            *(ushort4*)&uT[blk * UTP + i0] = o4;
        }
        __syncthreads();
        unsigned short* yb = y + (size_t)(ct * H + h) * L;
#pragma unroll
        for (int r = 0; r < 2; ++r) {
            int c = r * 256 + t;             // 512 chunks = 64 blk x 8
            int o = c >> 3, c8 = (c & 7) * 8;
            *(short8*)(yb + o * 64 + c8) = *(const short8*)&uT[o * UTP + c8];
        }
    }
}

// ---------------- MFMA GEMM(512x256 @ 256x64) + bias + GLU + residual(bf16) + channel-LN ----------------
// 512 threads, TL2=64 (measured best). NOTE: __launch_bounds__(512,4) caps total
// regs/wave at 128; acc=64 AGPR leaves ~64 arch VGPR -> no room for deeper W
// pipelining at source level (R5 W-batch attempt measured null).
__global__ __launch_bounds__(512, 4) void k_gemm(
    const unsigned short* __restrict__ y, unsigned short* __restrict__ u,
    const unsigned short* __restrict__ Wb, const float* __restrict__ bo,
    const float* __restrict__ lng, const float* __restrict__ lnb,
    float* __restrict__ outp)
{
    // yS lives: (1) y tile for MFMA [TL2*YPAD], (2) residual u tile [H x URP],
    // (3) LN-output restage. Sized for the max of the three.
    __shared__ __align__(16) unsigned short yS[H * URP];      // 36.9 KB
    __shared__ float bS[O2];
    __shared__ float lgS[H], lbS[H];
    __shared__ float redS[8][4][16], redQ[8][4][16];

    const int t = threadIdx.x;
    const int wv = t >> 6;
    const int lane = t & 63;
    const int lanei = lane & 15;
    const int quad = lane >> 4;
    const int b = blockIdx.x >> 6;           // L/TL2 = 64 tiles per batch
    const int l0 = (blockIdx.x & 63) * TL2;

    size_t abase[2][2];
#pragma unroll
    for (int p = 0; p < 2; ++p)
#pragma unroll
        for (int jj = 0; jj < 2; ++jj)
            abase[p][jj] = (size_t)(p * 256 + wv * 32 + jj * 16 + lanei) * H + quad * 8;

    // kt=0 W fragments issued before the barrier: pre-barrier vmcnt drain hides their L2 latency
    short8 a8p[4];
#pragma unroll
    for (int p = 0; p < 2; ++p)
#pragma unroll
        for (int jj = 0; jj < 2; ++jj)
            a8p[p * 2 + jj] = *(const short8*)(Wb + abase[p][jj]);

    {   // stage y tile (256h x 64l bf16) -> yS[l][h ^ 8*(l>>3)] (swizzled)
        const int i = t & 7, hr = t >> 3;    // i: l-octet 0..7, hr: 0..63
        const unsigned short* yb = y + (size_t)b * H * L + l0 + i * 8;
#pragma unroll
        for (int ps = 0; ps < 4; ++ps) {
            int h = ps * 64 + hr;
            short8 v8 = *(const short8*)(yb + (size_t)h * L);
#pragma unroll
            for (int r = 0; r < 8; ++r)
                yS[(i * 8 + r) * YPAD + (h ^ (8 * i))] = (unsigned short)v8[r];
        }
        if (t < O2) bS[t] = bo[t];
        if (t < H) { lgS[t] = lng[t]; lbS[t] = lnb[t]; }
    }
    __syncthreads();

    f32x4 acc[2][2][4];
#pragma unroll
    for (int p = 0; p < 2; ++p)
#pragma unroll
        for (int jj = 0; jj < 2; ++jj)
#pragma unroll
            for (int nt = 0; nt < 4; ++nt)
                acc[p][jj][nt] = (f32x4){0.f, 0.f, 0.f, 0.f};

#pragma unroll
    for (int kt = 0; kt < 8; ++kt) {
        // batch the 4 W-fragment loads of this kt: 4 L2 requests in flight
        // together instead of serialized load->MFMA->load chains
        short8 a8[4];
        if (kt == 0) {
            a8[0] = a8p[0]; a8[1] = a8p[1]; a8[2] = a8p[2]; a8[3] = a8p[3];
        } else {
#pragma unroll
            for (int q = 0; q < 4; ++q)
                a8[q] = *(const short8*)(Wb + abase[q >> 1][q & 1] + kt * 32);
        }
        short8 bfr[4];
#pragma unroll
        for (int nt = 0; nt < 4; ++nt) {
            int lp = nt * 16 + lanei;
            int a = (2 * nt + (lanei >> 3)) & 7;
            bfr[nt] = *(const short8*)&yS[lp * YPAD + ((kt * 32 + quad * 8) ^ (8 * a))];
        }
#pragma unroll
        for (int p = 0; p < 2; ++p)
#pragma unroll
            for (int jj = 0; jj < 2; ++jj) {
#pragma unroll
                for (int nt = 0; nt < 4; ++nt)
                    acc[p][jj][nt] = __builtin_amdgcn_mfma_f32_16x16x32_bf16(
                        a8[p * 2 + jj], bfr[nt], acc[p][jj][nt], 0, 0, 0);
            }
    }
    __syncthreads();   // all waves done reading yS -> safe to reuse

    // ---- stage residual u tile into yS with coalesced short8 loads ----
    unsigned short* ub = u + (size_t)b * H * L + l0;
#pragma unroll
    for (int r = 0; r < 4; ++r) {
        int c = r * 512 + t;                 // 2048 chunks = 256 rows x 8
        int o = c >> 3, c8 = (c & 7) * 8;
        *(short8*)&yS[o * URP + c8] = *(const short8*)(ub + (size_t)o * L + c8);
    }
    __syncthreads();

    // ---- epilogue: bias + GLU + residual(from LDS); LN stats ----
    float psum[4] = {0.f, 0.f, 0.f, 0.f}, psq[4] = {0.f, 0.f, 0.f, 0.f};
#pragma unroll
    for (int jj = 0; jj < 2; ++jj) {
#pragma unroll
        for (int nt = 0; nt < 4; ++nt) {
            int lc = nt * 16 + lanei;
#pragma unroll
            for (int reg = 0; reg < 4; ++reg) {
                int o = wv * 32 + jj * 16 + quad * 4 + reg;
                float a = acc[0][jj][nt][reg] + bS[o];
                float g = acc[1][jj][nt][reg] + bS[o + 256];
                float glu = a / (1.f + __expf(-g));
                float val = glu + bf2f(yS[o * URP + lc]);
                acc[0][jj][nt][reg] = val;
                psum[nt] += val;
                psq[nt] = fmaf(val, val, psq[nt]);
            }
        }
    }
#pragma unroll
    for (int nt = 0; nt < 4; ++nt) {
        psum[nt] += __shfl_xor(psum[nt], 16);
        psum[nt] += __shfl_xor(psum[nt], 32);
        psq[nt]  += __shfl_xor(psq[nt], 16);
        psq[nt]  += __shfl_xor(psq[nt], 32);
    }
    if (lane < 16) {
#pragma unroll
        for (int nt = 0; nt < 4; ++nt) {
            redS[wv][nt][lanei] = psum[nt];
            redQ[wv][nt][lanei] = psq[nt];
        }
    }
    __syncthreads();   // also guarantees all residual reads of yS completed
    float mcol[4], icol[4];
#pragma unroll
    for (int nt = 0; nt < 4; ++nt) {
        float s = 0.f, q = 0.f;
#pragma unroll
        for (int w = 0; w < 8; ++w) { s += redS[w][nt][lanei]; q += redQ[w][nt][lanei]; }
        float m = s * (1.0f / 256.0f);
        float v = q * (1.0f / 256.0f) - m * m;
        mcol[nt] = m;
        icol[nt] = rsqrtf(v + 1e-5f);
    }
    if (outp == nullptr) {
        // restage LN output through yS, then coalesced short8 stores
#pragma unroll
        for (int jj = 0; jj < 2; ++jj) {
#pragma unroll
            for (int nt = 0; nt < 4; ++nt) {
                int lc = nt * 16 + lanei;
#pragma unroll
                for (int reg = 0; reg < 4; ++reg) {
                    int o = wv * 32 + jj * 16 + quad * 4 + reg;
                    float val = acc[0][jj][nt][reg];
                    float ov = (val - mcol[nt]) * icol[nt] * lgS[o] + lbS[o];
                    yS[o * URP + lc] = f2bf(ov);
                }
            }
        }
        __syncthreads();
#pragma unroll
        for (int r = 0; r < 4; ++r) {
            int c = r * 512 + t;
            int o = c >> 3, c8 = (c & 7) * 8;
            *(short8*)(ub + (size_t)o * L + c8) = *(const short8*)&yS[o * URP + c8];
        }
    } else {
        // final layer: write fp32 transposed out (B,L,H) directly
#pragma unroll
        for (int jj = 0; jj < 2; ++jj) {
#pragma unroll
            for (int nt = 0; nt < 4; ++nt) {
                int lc = nt * 16 + lanei;
                int o0 = wv * 32 + jj * 16 + quad * 4;
                float4 ov;
#pragma unroll
                for (int reg = 0; reg < 4; ++reg) {
                    int o = o0 + reg;
                    float val = acc[0][jj][nt][reg];
                    ((float*)&ov)[reg] = (val - mcol[nt]) * icol[nt] * lgS[o] + lbS[o];
                }
                *(float4*)(outp + ((size_t)b * L + l0 + lc) * H + o0) = ov;
            }
        }
    }
}

extern "C" void kernel_launch(void* const* d_in, const int* in_sizes, int n_in,
                              void* d_out, int out_size, void* d_ws, size_t ws_size,
                              hipStream_t stream)
{
    const float* x      = (const float*)d_in[0];
    const float* log_dt = (const float*)d_in[1];
    const float* log_Ar = (const float*)d_in[2];
    const float* A_im   = (const float*)d_in[3];
    const float* C_re   = (const float*)d_in[4];
    const float* C_im   = (const float*)d_in[5];
    const float* Dv     = (const float*)d_in[6];
    const float* Wout   = (const float*)d_in[7];
    const float* bout   = (const float*)d_in[8];
    const float* lng    = (const float*)d_in[9];
    const float* lnb    = (const float*)d_in[10];
    float* out = (float*)d_out;

    unsigned short* u   = (unsigned short*)d_ws;                          // 16.8 MB
    unsigned short* Wb  = u + (size_t)B * H * L;                          // 1 MB
    unsigned short* TVc = Wb + (size_t)NL * O2 * H;                       // 17.8 MB
    unsigned short* Mm  = TVc + (size_t)NL * H * BLK * TVP;               // 9.4 MB
    float2* w64c        = (float2*)(Mm + (size_t)NL * H * BLK * MJP);     // 0.26 MB
    unsigned short* y   = (unsigned short*)(w64c + (size_t)NL * H * N2);  // 16.8 MB

    // 512 wcvt + 1024 mats + 4096 tr_xu blocks
    k_setup<<<5632, 256, 0, stream>>>(x, log_dt, log_Ar, A_im, C_re, C_im, Dv, Wout,
                                      Wb, TVc, Mm, w64c, u);
    for (int layer = 0; layer < NL; ++layer) {
        k_scan3<<<H * 8, 256, 0, stream>>>(u, Mm + (size_t)layer * H * BLK * MJP,
                                           TVc + (size_t)layer * H * BLK * TVP,
                                           w64c + (size_t)layer * H * N2, y);
        k_gemm<<<B * L / TL2, 512, 0, stream>>>(y, u, Wb + (size_t)layer * O2 * H,
                                                bout + layer * O2, lng + layer * H, lnb + layer * H,
                                                (layer == NL - 1) ? out : nullptr);
    }
}

// Round 8
// 272.234 us; speedup vs baseline: 1.3250x; 1.0830x over previous
//
#include <hip/hip_runtime.h>
#include <math.h>

#define B    8
#define L    4096
#define H    256
#define N2   32
#define NL   4
#define O2   512   // 2H
#define BLK  64    // scan block length
#define NBLK 64    // L/BLK
#define TVP  136   // TVc row stride (elems): 64 T + 64 Vc + 8 pad
#define MJP  72    // Mm row stride
#define UTP  72    // uT/ST LDS row stride (u16), 144B = 16B-mult
#define INP  68    // INC LDS row stride (f32), 272B = 16B-mult
#define TL2  64    // k_gemm l-tile
#define YPAD 264   // k_gemm yS row stride (u16)
#define URP  72    // k_gemm residual-tile LDS row stride (u16), 144B = 16B-mult
#define YSZ  20512 // per-tile LDS buffer (u16): max(64*YPAD,256*URP)+pad; 2x pushes LDS>80KB -> forced 1 block/CU

typedef __attribute__((ext_vector_type(8))) short short8;
typedef __attribute__((ext_vector_type(4))) float f32x4;

__device__ __forceinline__ unsigned short f2bf(float f)
{
    unsigned int u = __float_as_uint(f);
    unsigned int r = (u + 0x7fffu + ((u >> 16) & 1u)) >> 16;
    return (unsigned short)r;
}

__device__ __forceinline__ float bf2f(unsigned short v)
{
    return __uint_as_float(((unsigned int)v) << 16);
}

// fast GELU: x * sigmoid(1.5957691216(x + 0.044715 x^3)) — max err ~2e-3
__device__ __forceinline__ float gelu_f(float x)
{
    float t = 1.59576912161f * fmaf(0.044715f * x * x, x, x);
    return x / (1.f + __expf(-t));
}

// ---------------- merged setup: [0,512) wcvt | [512,1536) mats | [1536,5632) tr_xu ----------------
__global__ __launch_bounds__(256) void k_setup(
    const float* __restrict__ x, const float* __restrict__ log_dt,
    const float* __restrict__ log_Ar, const float* __restrict__ A_im,
    const float* __restrict__ C_re, const float* __restrict__ C_im,
    const float* __restrict__ Dv, const float* __restrict__ Wout,
    unsigned short* __restrict__ Wb, unsigned short* __restrict__ TVc,
    unsigned short* __restrict__ Mm, float2* __restrict__ w64c,
    unsigned short* __restrict__ u)
{
    // union: tr_xu uses 8.7 KB f32 tile; mats uses 27.6 KB staging
    __shared__ __align__(16) unsigned char smem_raw[27648];
    const int bid = blockIdx.x;
    const int t = threadIdx.x;

    if (bid < 512) {
        // ---- Wout fp32 -> bf16 ----
        int idx = (bid * 256 + t) * 4;
        float4 v = *(const float4*)(Wout + idx);
        ushort4 o;
        o.x = f2bf(v.x); o.y = f2bf(v.y); o.z = f2bf(v.z); o.w = f2bf(v.w);
        *(ushort4*)(Wb + idx) = o;
    } else if (bid < 1536) {
        // ---- build per-(layer,h): T|Vc, M, w^64 — one id per block ----
        unsigned short* tvS = (unsigned short*)smem_raw;      // [64*TVP] 17408 B
        unsigned short* mmS = tvS + BLK * TVP;                // [64*MJP]  9216 B
        float* kbS = (float*)(mmS + BLK * MJP);               // [64]       256 B
        float* cS  = kbS + BLK;                               // [6*32]     768 B
        const int id = bid - 512;                             // [0, 1024)
        const int layer = id >> 8, h = id & 255;
        if (t < 32) {
            // per-n constants in double, once; broadcast via LDS
            const int n0 = t;
            const int idx = (layer * H + h) * N2 + n0;
            double dt = exp((double)log_dt[layer * H + h]);
            double Ar = -exp((double)log_Ar[idx]);
            double Ai = (double)A_im[idx];
            double dtr = dt * Ar, dti = dt * Ai;
            double er = exp(dtr);
            double dwr = er * cos(dti), dwi = er * sin(dti);
            double numr = dwr - 1.0, numi = dwi;
            double den = Ar * Ar + Ai * Ai;
            double qr0 = (numr * Ar + numi * Ai) / den;
            double qi0 = (numi * Ar - numr * Ai) / den;
            double dcr = (double)C_re[idx], dci = (double)C_im[idx];
            cS[n0]       = (float)(2.0 * (dcr * qr0 - dci * qi0));  // cr
            cS[32 + n0]  = (float)(2.0 * (dcr * qi0 + dci * qr0));  // ci
            cS[64 + n0]  = (float)dwr;                              // wr
            cS[96 + n0]  = (float)dwi;                              // wi
            double rev = dti * 0.15915494309189535;                 // dti/2pi
            cS[128 + n0] = (float)(rev - floor(rev));               // revf (frac)
            cS[160 + n0] = (float)dtr;                              // dtrf
            // w^64 in closed form (double): better than 64 serial f32 muls
            double m64 = exp(64.0 * dtr);
            double a64 = 64.0 * dti;
            w64c[(layer * H + h) * N2 + n0] =
                make_float2((float)(m64 * cos(a64)), (float)(m64 * sin(a64)));
        }
        __syncthreads();
        const int n = t & 31, dg = t >> 5;    // each thread: 8 d-values, one n
        const float cr = cS[n], ci = cS[32 + n];
        const float wr = cS[64 + n], wi = cS[96 + n];
        const float revf = cS[128 + n], dtrf = cS[160 + n];
#pragma unroll
        for (int i = 0; i < 8; ++i) {
            const int d = dg * 8 + i;
            // w^d = exp(d*dtr) * cis(2pi * frac(d*revf)) — no serial dependence
            float ph = (float)d * revf;
            ph = (ph - floorf(ph)) * 6.28318530718f;
            float mag = __expf((float)d * dtrf);
            float vr = mag * __cosf(ph);
            float vi = mag * __sinf(ph);
            float pk = fmaf(cr, vr, -(ci * vi));
            pk += __shfl_xor(pk, 1);  pk += __shfl_xor(pk, 2);
            pk += __shfl_xor(pk, 4);  pk += __shfl_xor(pk, 8);
            pk += __shfl_xor(pk, 16);
            if (n == 0) kbS[d] = pk;
            mmS[n * MJP + (63 - d)]        = f2bf(vr);
            mmS[(32 + n) * MJP + (63 - d)] = f2bf(vi);
            float v1r = vr * wr - vi * wi;            // w^{d+1}
            float v1i = vr * wi + vi * wr;
            tvS[d * TVP + 64 + n] = f2bf(fmaf(cr, v1r, -(ci * v1i)));
            tvS[d * TVP + 96 + n] = f2bf(-fmaf(cr, v1i, ci * v1r));
        }
        __syncthreads();
        {   // Toeplitz T fill: row r = t>>2, 16 cols -> two aligned short8 stores
            const int r = t >> 2, c0 = (t & 3) * 16;
            const float diag = kbS[0] + Dv[layer * H + h];
            short8 o8[2];
#pragma unroll
            for (int j = 0; j < 16; ++j) {
                int c = c0 + j;
                float val = (c > r) ? 0.f : ((c == r) ? diag : kbS[r - c]);
                o8[j >> 3][j & 7] = (short)f2bf(val);
            }
            *(short8*)&tvS[r * TVP + c0]     = o8[0];
            *(short8*)&tvS[r * TVP + c0 + 8] = o8[1];
        }
        __syncthreads();
        // coalesced blast-out (16 B/lane chunks)
        unsigned short* tv = TVc + (size_t)(layer * H + h) * BLK * TVP;
        unsigned short* mm = Mm + (size_t)(layer * H + h) * BLK * MJP;
        for (int c = t; c < (BLK * TVP) / 8; c += 256)
            *(short8*)(tv + c * 8) = *(const short8*)&tvS[c * 8];
        for (int c = t; c < (BLK * MJP) / 8; c += 256)
            *(short8*)(mm + c * 8) = *(const short8*)&mmS[c * 8];
    } else {
        // ---- transpose x (B,L,H) fp32 -> u (B,H,L) bf16 : 64l x 32h tiles, 4096 blocks ----
        float* sh = (float*)smem_raw;        // [32*68]
        const int rb = bid - 1536;           // [0, 4096)
        const int hx = rb & 7, ly = (rb >> 3) & 63, b = rb >> 9;
        const int h0 = hx * 32, l0 = ly * 64;
        const int tx = t & 7, ty = t >> 3;   // load: tx = h-quad (8x float4 = 32 h), ty = l-row (32)
        const float* xb = x + ((size_t)b * L + l0) * H + h0;
#pragma unroll
        for (int i = 0; i < 2; ++i) {
            int l = ty + i * 32;
            float4 v = *(const float4*)(xb + (size_t)l * H + tx * 4);
            sh[(tx * 4 + 0) * 68 + l] = v.x;
            sh[(tx * 4 + 1) * 68 + l] = v.y;
            sh[(tx * 4 + 2) * 68 + l] = v.z;
            sh[(tx * 4 + 3) * 68 + l] = v.w;
        }
        __syncthreads();
        // write: 32 h-rows x 64 u16 (128B contiguous per row)
        const int hh = t >> 3, cc = (t & 7) * 8;
        const float* row = &sh[hh * 68 + cc];
        short8 o8;
#pragma unroll
        for (int j = 0; j < 8; ++j) o8[j] = (short)f2bf(row[j]);
        *(short8*)(u + ((size_t)b * H + h0 + hh) * L + l0 + cc) = o8;
    }
}

// ---------------- fused scan: GEMM-A + 2-level chain + GEMM-B (row-ownership, round-8 layout) ----------------
__global__ __launch_bounds__(256) void k_scan3(
    const unsigned short* __restrict__ u, const unsigned short* __restrict__ Mm_l,
    const unsigned short* __restrict__ TVc_l, const float2* __restrict__ w64c_l,
    unsigned short* __restrict__ y)
{
    __shared__ __align__(16) unsigned short uT[BLK * UTP];   // 9.2 KB
    __shared__ __align__(16) unsigned short ST[BLK * UTP];   // 9.2 KB
    __shared__ __align__(16) float INC[BLK * INP];           // 17.4 KB
    __shared__ float2 cLd[4][32];
    const int t = threadIdx.x;
    const int wv = t >> 6, lane = t & 63;
    const int lanei = lane & 15, quad = lane >> 4;
    // XCD-sharing decomposition: h = bid&255 puts the 8 batch-siblings that read
    // the same Mm[h]/TVc[h] on the same XCD residue (256%8==0) -> mats L2-shared.
    const int h = blockIdx.x & 255, ct = blockIdx.x >> 8;    // ct = batch
    const unsigned short* ub = u + (size_t)(ct * H + h) * L;

    // early register prefetch of all mats operands (hides L2/HBM latency under
    // staging + scan; hipcc won't hoist loads across __syncthreads)
    const unsigned short* arowA = Mm_l + (size_t)h * BLK * MJP + (wv * 16 + lanei) * MJP + quad * 8;
    short8 mA[2];
    mA[0] = *(const short8*)(arowA);
    mA[1] = *(const short8*)(arowA + 32);
    const unsigned short* arowB = TVc_l + (size_t)h * BLK * TVP + (wv * 16 + lanei) * TVP + quad * 8;
    short8 tB[4];
#pragma unroll
    for (int kt = 0; kt < 4; ++kt)
        tB[kt] = *(const short8*)(arowB + kt * 32);
    const float2 w64 = w64c_l[h * N2 + (lane & 31)];

    {   // stage uT[col=blk][j] bf16 (direct copy)
        int col = t >> 2, q = t & 3;
        *(short8*)&uT[col * UTP + q * 16]     = *(const short8*)(ub + col * 64 + q * 16);
        *(short8*)&uT[col * UTP + q * 16 + 8] = *(const short8*)(ub + col * 64 + q * 16 + 8);
    }
    __syncthreads();

    // ---- GEMM-A: INC[blk][k] = sum_j M[k][j] * u[blk*64+j] ----
    {
        f32x4 acc[4];
#pragma unroll
        for (int nt = 0; nt < 4; ++nt) acc[nt] = (f32x4){0.f, 0.f, 0.f, 0.f};
#pragma unroll
        for (int kt = 0; kt < 2; ++kt) {
#pragma unroll
            for (int nt = 0; nt < 4; ++nt) {
                short8 b8 = *(const short8*)&uT[(nt * 16 + lanei) * UTP + kt * 32 + quad * 8];
                acc[nt] = __builtin_amdgcn_mfma_f32_16x16x32_bf16(mA[kt], b8, acc[nt], 0, 0, 0);
            }
        }
#pragma unroll
        for (int nt = 0; nt < 4; ++nt)
            *(f32x4*)&INC[(nt * 16 + lanei) * INP + wv * 16 + quad * 4] = acc[nt];
    }
    __syncthreads();

    // ---- chain: two-level parallel scan (each wave owns 16 blocks) ----
    const int n = lane & 31;
    float Pr[16], Pi[16];
    float w1r = 1.f, w1i = 0.f;
    if (lane < 32) {
        float sr = 0.f, si = 0.f;
        const int base = wv * 16;
#pragma unroll
        for (int k = 0; k < 16; ++k) {
            Pr[k] = sr; Pi[k] = si;
            float ir = INC[(base + k) * INP + n];
            float ii = INC[(base + k) * INP + 32 + n];
            float nr = fmaf(w64.x, sr, fmaf(-w64.y, si, ir));
            float ni = fmaf(w64.x, si, fmaf(w64.y, sr, ii));
            sr = nr; si = ni;
        }
        cLd[wv][n] = make_float2(sr, si);
        float ar = w64.x, ai = w64.y;
#pragma unroll
        for (int q = 0; q < 4; ++q) {         // w64^16
            float nr2 = ar * ar - ai * ai;
            float ni2 = 2.f * ar * ai;
            ar = nr2; ai = ni2;
        }
        w1r = ar; w1i = ai;
    }
    __syncthreads();
    if (lane < 32) {
        float Cr = 0.f, Ci = 0.f;
        for (int wp = 0; wp < wv; ++wp) {
            float2 Lw = cLd[wp][n];
            float nr = fmaf(w1r, Cr, fmaf(-w1i, Ci, Lw.x));
            float ni = fmaf(w1r, Ci, fmaf(w1i, Cr, Lw.y));
            Cr = nr; Ci = ni;
        }
        float pr = 1.f, pi = 0.f;
#pragma unroll
        for (int k = 0; k < 16; ++k) {
            int blk = wv * 16 + k;
            float Sr = fmaf(pr, Cr, fmaf(-pi, Ci, Pr[k]));
            float Si = fmaf(pr, Ci, fmaf(pi, Cr, Pi[k]));
            ST[blk * UTP + n]      = f2bf(Sr);
            ST[blk * UTP + 32 + n] = f2bf(Si);
            float npr = pr * w64.x - pi * w64.y;
            float npi = pr * w64.y + pi * w64.x;
            pr = npr; pi = npi;
        }
    }
    __syncthreads();

    // ---- GEMM-B: y = gelu(T*U + Vc*S); restage via uT -> coalesced 16B stores ----
    {
        f32x4 acc[4];
#pragma unroll
        for (int nt = 0; nt < 4; ++nt) acc[nt] = (f32x4){0.f, 0.f, 0.f, 0.f};
#pragma unroll
        for (int kt = 0; kt < 4; ++kt) {
            const unsigned short* bb = (kt < 2) ? uT : ST;
            int ko = (kt & 1) * 32 + quad * 8;
#pragma unroll
            for (int nt = 0; nt < 4; ++nt) {
                short8 b8 = *(const short8*)&bb[(nt * 16 + lanei) * UTP + ko];
                acc[nt] = __builtin_amdgcn_mfma_f32_16x16x32_bf16(tB[kt], b8, acc[nt], 0, 0, 0);
            }
        }
        __syncthreads();   // all waves done reading uT -> safe to reuse
#pragma unroll
        for (int nt = 0; nt < 4; ++nt) {
            int blk = nt * 16 + lanei;
            int i0 = wv * 16 + quad * 4;
            ushort4 o4;
            o4.x = f2bf(gelu_f(acc[nt][0]));
            o4.y = f2bf(gelu_f(acc[nt][1]));
            o4.z = f2bf(gelu_f(acc[nt][2]));
            o4.w = f2bf(gelu_f(acc[nt][3]));
            *(ushort4*)&uT[blk * UTP + i0] = o4;
        }
        __syncthreads();
        unsigned short* yb = y + (size_t)(ct * H + h) * L;
#pragma unroll
        for (int r = 0; r < 2; ++r) {
            int c = r * 256 + t;             // 512 chunks = 64 blk x 8
            int o = c >> 3, c8 = (c & 7) * 8;
            *(short8*)(yb + o * 64 + c8) = *(const short8*)&uT[o * UTP + c8];
        }
    }
}

// ---------------- MFMA GEMM + bias + GLU + residual + channel-LN: dual-tile, 1 block/CU ----------------
// Grid 256 (1 block/CU, forced by 88KB LDS), launch_bounds(512,2) -> 256-VGPR budget.
// Each block processes tiles bid and bid+256 JOINTLY: one W-fragment load feeds 32
// MFMAs (W identical across tiles -> W L2 traffic halved, load:compute ratio 2x),
// both y-tiles staged up-front (2x stage MLP), dual 64-reg accumulators (affordable
// only at the 256-reg budget; the old 2-block/CU config was phase-aligned and
// register-walled at 128 -> 4.3x over its HBM floor).
__global__ __launch_bounds__(512, 2) void k_gemm(
    const unsigned short* __restrict__ y, unsigned short* __restrict__ u,
    const unsigned short* __restrict__ Wb, const float* __restrict__ bo,
    const float* __restrict__ lng, const float* __restrict__ lnb,
    float* __restrict__ outp)
{
    __shared__ __align__(16) unsigned short ySA[YSZ];         // 41 KB (tile A: y-stage / residual / restage)
    __shared__ __align__(16) unsigned short ySB[YSZ];         // 41 KB (tile B)
    __shared__ float bS[O2];
    __shared__ float lgS[H], lbS[H];
    __shared__ float redS[8][4][16], redQ[8][4][16];

    const int t = threadIdx.x;
    const int wv = t >> 6;
    const int lane = t & 63;
    const int lanei = lane & 15;
    const int quad = lane >> 4;
    const int idxA = blockIdx.x;             // tile A
    const int idxB = blockIdx.x + 256;       // tile B
    const int bA = idxA >> 6, l0A = (idxA & 63) * TL2;
    const int bB = idxB >> 6, l0B = (idxB & 63) * TL2;

    size_t abase[2][2];
#pragma unroll
    for (int p = 0; p < 2; ++p)
#pragma unroll
        for (int jj = 0; jj < 2; ++jj)
            abase[p][jj] = (size_t)(p * 256 + wv * 32 + jj * 16 + lanei) * H + quad * 8;

    {   // stage BOTH y tiles (256h x 64l bf16 each) -> ySx[l][h ^ 8*(l>>3)] (swizzled)
        const int i = t & 7, hr = t >> 3;    // i: l-octet 0..7, hr: 0..63
        const unsigned short* ybA = y + (size_t)bA * H * L + l0A + i * 8;
        const unsigned short* ybB = y + (size_t)bB * H * L + l0B + i * 8;
        short8 vA[4], vB[4];
#pragma unroll
        for (int ps = 0; ps < 4; ++ps)
            vA[ps] = *(const short8*)(ybA + (size_t)(ps * 64 + hr) * L);
#pragma unroll
        for (int ps = 0; ps < 4; ++ps)
            vB[ps] = *(const short8*)(ybB + (size_t)(ps * 64 + hr) * L);
#pragma unroll
        for (int ps = 0; ps < 4; ++ps) {
            int h = ps * 64 + hr;
#pragma unroll
            for (int r = 0; r < 8; ++r)
                ySA[(i * 8 + r) * YPAD + (h ^ (8 * i))] = (unsigned short)vA[ps][r];
        }
#pragma unroll
        for (int ps = 0; ps < 4; ++ps) {
            int h = ps * 64 + hr;
#pragma unroll
            for (int r = 0; r < 8; ++r)
                ySB[(i * 8 + r) * YPAD + (h ^ (8 * i))] = (unsigned short)vB[ps][r];
        }
        if (t < O2) bS[t] = bo[t];
        if (t < H) { lgS[t] = lng[t]; lbS[t] = lnb[t]; }
    }
    __syncthreads();

    f32x4 accA[2][2][4], accB[2][2][4];
#pragma unroll
    for (int p = 0; p < 2; ++p)
#pragma unroll
        for (int jj = 0; jj < 2; ++jj)
#pragma unroll
            for (int nt = 0; nt < 4; ++nt) {
                accA[p][jj][nt] = (f32x4){0.f, 0.f, 0.f, 0.f};
                accB[p][jj][nt] = (f32x4){0.f, 0.f, 0.f, 0.f};
            }

    // joint MFMA loop: one W-fragment batch per kt drives both tiles
#pragma unroll
    for (int kt = 0; kt < 8; ++kt) {
        short8 a8[4];
#pragma unroll
        for (int q = 0; q < 4; ++q)
            a8[q] = *(const short8*)(Wb + abase[q >> 1][q & 1] + kt * 32);
        short8 bfrA[4], bfrB[4];
#pragma unroll
        for (int nt = 0; nt < 4; ++nt) {
            int lp = nt * 16 + lanei;
            int a = (2 * nt + (lanei >> 3)) & 7;
            int off = lp * YPAD + ((kt * 32 + quad * 8) ^ (8 * a));
            bfrA[nt] = *(const short8*)&ySA[off];
            bfrB[nt] = *(const short8*)&ySB[off];
        }
#pragma unroll
        for (int p = 0; p < 2; ++p)
#pragma unroll
            for (int jj = 0; jj < 2; ++jj) {
#pragma unroll
                for (int nt = 0; nt < 4; ++nt) {
                    accA[p][jj][nt] = __builtin_amdgcn_mfma_f32_16x16x32_bf16(
                        a8[p * 2 + jj], bfrA[nt], accA[p][jj][nt], 0, 0, 0);
                    accB[p][jj][nt] = __builtin_amdgcn_mfma_f32_16x16x32_bf16(
                        a8[p * 2 + jj], bfrB[nt], accB[p][jj][nt], 0, 0, 0);
                }
            }
    }

    // ---- residual staging A (issue loads, then LDS write after barrier) ----
    unsigned short* ubA = u + (size_t)bA * H * L + l0A;
    unsigned short* ubB = u + (size_t)bB * H * L + l0B;
    short8 rA[4];
#pragma unroll
    for (int r = 0; r < 4; ++r) {
        int c = r * 512 + t;
        int o = c >> 3, c8 = (c & 7) * 8;
        rA[r] = *(const short8*)(ubA + (size_t)o * L + c8);
    }
    __syncthreads();   // all waves done reading ySA/ySB -> safe to reuse
#pragma unroll
    for (int r = 0; r < 4; ++r) {
        int c = r * 512 + t;
        int o = c >> 3, c8 = (c & 7) * 8;
        *(short8*)&ySA[o * URP + c8] = rA[r];
    }
    // issue residual B loads now: in flight across epilogue A
    short8 rB[4];
#pragma unroll
    for (int r = 0; r < 4; ++r) {
        int c = r * 512 + t;
        int o = c >> 3, c8 = (c & 7) * 8;
        rB[r] = *(const short8*)(ubB + (size_t)o * L + c8);
    }
    __syncthreads();

    // =========== epilogue A ===========
    {
        float psum[4] = {0.f, 0.f, 0.f, 0.f}, psq[4] = {0.f, 0.f, 0.f, 0.f};
#pragma unroll
        for (int jj = 0; jj < 2; ++jj) {
#pragma unroll
            for (int nt = 0; nt < 4; ++nt) {
                int lc = nt * 16 + lanei;
#pragma unroll
                for (int reg = 0; reg < 4; ++reg) {
                    int o = wv * 32 + jj * 16 + quad * 4 + reg;
                    float a = accA[0][jj][nt][reg] + bS[o];
                    float g = accA[1][jj][nt][reg] + bS[o + 256];
                    float glu = a / (1.f + __expf(-g));
                    float val = glu + bf2f(ySA[o * URP + lc]);
                    accA[0][jj][nt][reg] = val;
                    psum[nt] += val;
                    psq[nt] = fmaf(val, val, psq[nt]);
                }
            }
        }
#pragma unroll
        for (int nt = 0; nt < 4; ++nt) {
            psum[nt] += __shfl_xor(psum[nt], 16);
            psum[nt] += __shfl_xor(psum[nt], 32);
            psq[nt]  += __shfl_xor(psq[nt], 16);
            psq[nt]  += __shfl_xor(psq[nt], 32);
        }
        if (lane < 16) {
#pragma unroll
            for (int nt = 0; nt < 4; ++nt) {
                redS[wv][nt][lanei] = psum[nt];
                redQ[wv][nt][lanei] = psq[nt];
            }
        }
        __syncthreads();
        float mcol[4], icol[4];
#pragma unroll
        for (int nt = 0; nt < 4; ++nt) {
            float s = 0.f, q = 0.f;
#pragma unroll
            for (int w = 0; w < 8; ++w) { s += redS[w][nt][lanei]; q += redQ[w][nt][lanei]; }
            float m = s * (1.0f / 256.0f);
            float v = q * (1.0f / 256.0f) - m * m;
            mcol[nt] = m;
            icol[nt] = rsqrtf(v + 1e-5f);
        }
        if (outp == nullptr) {
#pragma unroll
            for (int jj = 0; jj < 2; ++jj) {
#pragma unroll
                for (int nt = 0; nt < 4; ++nt) {
                    int lc = nt * 16 + lanei;
#pragma unroll
                    for (int reg = 0; reg < 4; ++reg) {
                        int o = wv * 32 + jj * 16 + quad * 4 + reg;
                        float val = accA[0][jj][nt][reg];
                        float ov = (val - mcol[nt]) * icol[nt] * lgS[o] + lbS[o];
                        ySA[o * URP + lc] = f2bf(ov);
                    }
                }
            }
            __syncthreads();
#pragma unroll
            for (int r = 0; r < 4; ++r) {
                int c = r * 512 + t;
                int o = c >> 3, c8 = (c & 7) * 8;
                *(short8*)(ubA + (size_t)o * L + c8) = *(const short8*)&ySA[o * URP + c8];
            }
        } else {
#pragma unroll
            for (int jj = 0; jj < 2; ++jj) {
#pragma unroll
                for (int nt = 0; nt < 4; ++nt) {
                    int lc = nt * 16 + lanei;
                    int o0 = wv * 32 + jj * 16 + quad * 4;
                    float4 ov;
#pragma unroll
                    for (int reg = 0; reg < 4; ++reg) {
                        int o = o0 + reg;
                        float val = accA[0][jj][nt][reg];
                        ((float*)&ov)[reg] = (val - mcol[nt]) * icol[nt] * lgS[o] + lbS[o];
                    }
                    *(float4*)(outp + ((size_t)bA * L + l0A + lc) * H + o0) = ov;
                }
            }
            __syncthreads();   // keep phase structure identical in both paths
        }
    }

    // ---- residual staging B ----
#pragma unroll
    for (int r = 0; r < 4; ++r) {
        int c = r * 512 + t;
        int o = c >> 3, c8 = (c & 7) * 8;
        *(short8*)&ySB[o * URP + c8] = rB[r];
    }
    __syncthreads();

    // =========== epilogue B ===========
    {
        float psum[4] = {0.f, 0.f, 0.f, 0.f}, psq[4] = {0.f, 0.f, 0.f, 0.f};
#pragma unroll
        for (int jj = 0; jj < 2; ++jj) {
#pragma unroll
            for (int nt = 0; nt < 4; ++nt) {
                int lc = nt * 16 + lanei;
#pragma unroll
                for (int reg = 0; reg < 4; ++reg) {
                    int o = wv * 32 + jj * 16 + quad * 4 + reg;
                    float a = accB[0][jj][nt][reg] + bS[o];
                    float g = accB[1][jj][nt][reg] + bS[o + 256];
                    float glu = a / (1.f + __expf(-g));
                    float val = glu + bf2f(ySB[o * URP + lc]);
                    accB[0][jj][nt][reg] = val;
                    psum[nt] += val;
                    psq[nt] = fmaf(val, val, psq[nt]);
                }
            }
        }
#pragma unroll
        for (int nt = 0; nt < 4; ++nt) {
            psum[nt] += __shfl_xor(psum[nt], 16);
            psum[nt] += __shfl_xor(psum[nt], 32);
            psq[nt]  += __shfl_xor(psq[nt], 16);
            psq[nt]  += __shfl_xor(psq[nt], 32);
        }
        if (lane < 16) {
#pragma unroll
            for (int nt = 0; nt < 4; ++nt) {
                redS[wv][nt][lanei] = psum[nt];
                redQ[wv][nt][lanei] = psq[nt];
            }
        }
        __syncthreads();
        float mcol[4], icol[4];
#pragma unroll
        for (int nt = 0; nt < 4; ++nt) {
            float s = 0.f, q = 0.f;
#pragma unroll
            for (int w = 0; w < 8; ++w) { s += redS[w][nt][lanei]; q += redQ[w][nt][lanei]; }
            float m = s * (1.0f / 256.0f);
            float v = q * (1.0f / 256.0f) - m * m;
            mcol[nt] = m;
            icol[nt] = rsqrtf(v + 1e-5f);
        }
        if (outp == nullptr) {
#pragma unroll
            for (int jj = 0; jj < 2; ++jj) {
#pragma unroll
                for (int nt = 0; nt < 4; ++nt) {
                    int lc = nt * 16 + lanei;
#pragma unroll
                    for (int reg = 0; reg < 4; ++reg) {
                        int o = wv * 32 + jj * 16 + quad * 4 + reg;
                        float val = accB[0][jj][nt][reg];
                        float ov = (val - mcol[nt]) * icol[nt] * lgS[o] + lbS[o];
                        ySB[o * URP + lc] = f2bf(ov);
                    }
                }
            }
            __syncthreads();
#pragma unroll
            for (int r = 0; r < 4; ++r) {
                int c = r * 512 + t;
                int o = c >> 3, c8 = (c & 7) * 8;
                *(short8*)(ubB + (size_t)o * L + c8) = *(const short8*)&ySB[o * URP + c8];
            }
        } else {
#pragma unroll
            for (int jj = 0; jj < 2; ++jj) {
#pragma unroll
                for (int nt = 0; nt < 4; ++nt) {
                    int lc = nt * 16 + lanei;
                    int o0 = wv * 32 + jj * 16 + quad * 4;
                    float4 ov;
#pragma unroll
                    for (int reg = 0; reg < 4; ++reg) {
                        int o = o0 + reg;
                        float val = accB[0][jj][nt][reg];
                        ((float*)&ov)[reg] = (val - mcol[nt]) * icol[nt] * lgS[o] + lbS[o];
                    }
                    *(float4*)(outp + ((size_t)bB * L + l0B + lc) * H + o0) = ov;
                }
            }
        }
    }
}

extern "C" void kernel_launch(void* const* d_in, const int* in_sizes, int n_in,
                              void* d_out, int out_size, void* d_ws, size_t ws_size,
                              hipStream_t stream)
{
    const float* x      = (const float*)d_in[0];
    const float* log_dt = (const float*)d_in[1];
    const float* log_Ar = (const float*)d_in[2];
    const float* A_im   = (const float*)d_in[3];
    const float* C_re   = (const float*)d_in[4];
    const float* C_im   = (const float*)d_in[5];
    const float* Dv     = (const float*)d_in[6];
    const float* Wout   = (const float*)d_in[7];
    const float* bout   = (const float*)d_in[8];
    const float* lng    = (const float*)d_in[9];
    const float* lnb    = (const float*)d_in[10];
    float* out = (float*)d_out;

    unsigned short* u   = (unsigned short*)d_ws;                          // 16.8 MB
    unsigned short* Wb  = u + (size_t)B * H * L;                          // 1 MB
    unsigned short* TVc = Wb + (size_t)NL * O2 * H;                       // 17.8 MB
    unsigned short* Mm  = TVc + (size_t)NL * H * BLK * TVP;               // 9.4 MB
    float2* w64c        = (float2*)(Mm + (size_t)NL * H * BLK * MJP);     // 0.26 MB
    unsigned short* y   = (unsigned short*)(w64c + (size_t)NL * H * N2);  // 16.8 MB

    // 512 wcvt + 1024 mats + 4096 tr_xu blocks
    k_setup<<<5632, 256, 0, stream>>>(x, log_dt, log_Ar, A_im, C_re, C_im, Dv, Wout,
                                      Wb, TVc, Mm, w64c, u);
    for (int layer = 0; layer < NL; ++layer) {
        k_scan3<<<H * 8, 256, 0, stream>>>(u, Mm + (size_t)layer * H * BLK * MJP,
                                           TVc + (size_t)layer * H * BLK * TVP,
                                           w64c + (size_t)layer * H * N2, y);
        k_gemm<<<256, 512, 0, stream>>>(y, u, Wb + (size_t)layer * O2 * H,
                                        bout + layer * O2, lng + layer * H, lnb + layer * H,
                                        (layer == NL - 1) ? out : nullptr);
    }
}

// Round 10
// 272.231 us; speedup vs baseline: 1.3250x; 1.0000x over previous
//
#include <hip/hip_runtime.h>
#include <math.h>

#define B    8
#define L    4096
#define H    256
#define N2   32
#define NL   4
#define O2   512   // 2H
#define BLK  64    // scan block length
#define NBLK 64    // L/BLK
#define TVP  136   // TVc row stride (elems): 64 T + 64 Vc + 8 pad
#define MJP  72    // Mm row stride
#define UTP  72    // uT/ST LDS row stride (u16), 144B = 16B-mult
#define INP  68    // INC LDS row stride (f32), 272B = 16B-mult
#define TL2  64    // k_gemm l-tile
#define YPAD 264   // k_gemm yS row stride (u16)
#define YSZ  16896 // per-tile LDS buffer (u16): max(64*YPAD=16896, 256*64=16384)
// residual tile now stride-64 with XOR swizzle (col ^ (o&7)<<3) instead of +8 pad:
// drops block LDS 90.6->75.8 KB. A/B test: if occupancy was LDS-capped -> 2 blocks/CU.

typedef __attribute__((ext_vector_type(8))) short short8;
typedef __attribute__((ext_vector_type(4))) float f32x4;

__device__ __forceinline__ unsigned short f2bf(float f)
{
    unsigned int u = __float_as_uint(f);
    unsigned int r = (u + 0x7fffu + ((u >> 16) & 1u)) >> 16;
    return (unsigned short)r;
}

__device__ __forceinline__ float bf2f(unsigned short v)
{
    return __uint_as_float(((unsigned int)v) << 16);
}

// fast GELU: x * sigmoid(1.5957691216(x + 0.044715 x^3)) — max err ~2e-3
__device__ __forceinline__ float gelu_f(float x)
{
    float t = 1.59576912161f * fmaf(0.044715f * x * x, x, x);
    return x / (1.f + __expf(-t));
}

// ---------------- merged setup: [0,512) wcvt | [512,1536) mats | [1536,5632) tr_xu ----------------
__global__ __launch_bounds__(256) void k_setup(
    const float* __restrict__ x, const float* __restrict__ log_dt,
    const float* __restrict__ log_Ar, const float* __restrict__ A_im,
    const float* __restrict__ C_re, const float* __restrict__ C_im,
    const float* __restrict__ Dv, const float* __restrict__ Wout,
    unsigned short* __restrict__ Wb, unsigned short* __restrict__ TVc,
    unsigned short* __restrict__ Mm, float2* __restrict__ w64c,
    unsigned short* __restrict__ u)
{
    // union: tr_xu uses 8.7 KB f32 tile; mats uses 27.6 KB staging
    __shared__ __align__(16) unsigned char smem_raw[27648];
    const int bid = blockIdx.x;
    const int t = threadIdx.x;

    if (bid < 512) {
        // ---- Wout fp32 -> bf16 ----
        int idx = (bid * 256 + t) * 4;
        float4 v = *(const float4*)(Wout + idx);
        ushort4 o;
        o.x = f2bf(v.x); o.y = f2bf(v.y); o.z = f2bf(v.z); o.w = f2bf(v.w);
        *(ushort4*)(Wb + idx) = o;
    } else if (bid < 1536) {
        // ---- build per-(layer,h): T|Vc, M, w^64 — one id per block ----
        unsigned short* tvS = (unsigned short*)smem_raw;      // [64*TVP] 17408 B
        unsigned short* mmS = tvS + BLK * TVP;                // [64*MJP]  9216 B
        float* kbS = (float*)(mmS + BLK * MJP);               // [64]       256 B
        float* cS  = kbS + BLK;                               // [6*32]     768 B
        const int id = bid - 512;                             // [0, 1024)
        const int layer = id >> 8, h = id & 255;
        if (t < 32) {
            // per-n constants in double, once; broadcast via LDS
            const int n0 = t;
            const int idx = (layer * H + h) * N2 + n0;
            double dt = exp((double)log_dt[layer * H + h]);
            double Ar = -exp((double)log_Ar[idx]);
            double Ai = (double)A_im[idx];
            double dtr = dt * Ar, dti = dt * Ai;
            double er = exp(dtr);
            double dwr = er * cos(dti), dwi = er * sin(dti);
            double numr = dwr - 1.0, numi = dwi;
            double den = Ar * Ar + Ai * Ai;
            double qr0 = (numr * Ar + numi * Ai) / den;
            double qi0 = (numi * Ar - numr * Ai) / den;
            double dcr = (double)C_re[idx], dci = (double)C_im[idx];
            cS[n0]       = (float)(2.0 * (dcr * qr0 - dci * qi0));  // cr
            cS[32 + n0]  = (float)(2.0 * (dcr * qi0 + dci * qr0));  // ci
            cS[64 + n0]  = (float)dwr;                              // wr
            cS[96 + n0]  = (float)dwi;                              // wi
            double rev = dti * 0.15915494309189535;                 // dti/2pi
            cS[128 + n0] = (float)(rev - floor(rev));               // revf (frac)
            cS[160 + n0] = (float)dtr;                              // dtrf
            // w^64 in closed form (double): better than 64 serial f32 muls
            double m64 = exp(64.0 * dtr);
            double a64 = 64.0 * dti;
            w64c[(layer * H + h) * N2 + n0] =
                make_float2((float)(m64 * cos(a64)), (float)(m64 * sin(a64)));
        }
        __syncthreads();
        const int n = t & 31, dg = t >> 5;    // each thread: 8 d-values, one n
        const float cr = cS[n], ci = cS[32 + n];
        const float wr = cS[64 + n], wi = cS[96 + n];
        const float revf = cS[128 + n], dtrf = cS[160 + n];
#pragma unroll
        for (int i = 0; i < 8; ++i) {
            const int d = dg * 8 + i;
            // w^d = exp(d*dtr) * cis(2pi * frac(d*revf)) — no serial dependence
            float ph = (float)d * revf;
            ph = (ph - floorf(ph)) * 6.28318530718f;
            float mag = __expf((float)d * dtrf);
            float vr = mag * __cosf(ph);
            float vi = mag * __sinf(ph);
            float pk = fmaf(cr, vr, -(ci * vi));
            pk += __shfl_xor(pk, 1);  pk += __shfl_xor(pk, 2);
            pk += __shfl_xor(pk, 4);  pk += __shfl_xor(pk, 8);
            pk += __shfl_xor(pk, 16);
            if (n == 0) kbS[d] = pk;
            mmS[n * MJP + (63 - d)]        = f2bf(vr);
            mmS[(32 + n) * MJP + (63 - d)] = f2bf(vi);
            float v1r = vr * wr - vi * wi;            // w^{d+1}
            float v1i = vr * wi + vi * wr;
            tvS[d * TVP + 64 + n] = f2bf(fmaf(cr, v1r, -(ci * v1i)));
            tvS[d * TVP + 96 + n] = f2bf(-fmaf(cr, v1i, ci * v1r));
        }
        __syncthreads();
        {   // Toeplitz T fill: row r = t>>2, 16 cols -> two aligned short8 stores
            const int r = t >> 2, c0 = (t & 3) * 16;
            const float diag = kbS[0] + Dv[layer * H + h];
            short8 o8[2];
#pragma unroll
            for (int j = 0; j < 16; ++j) {
                int c = c0 + j;
                float val = (c > r) ? 0.f : ((c == r) ? diag : kbS[r - c]);
                o8[j >> 3][j & 7] = (short)f2bf(val);
            }
            *(short8*)&tvS[r * TVP + c0]     = o8[0];
            *(short8*)&tvS[r * TVP + c0 + 8] = o8[1];
        }
        __syncthreads();
        // coalesced blast-out (16 B/lane chunks)
        unsigned short* tv = TVc + (size_t)(layer * H + h) * BLK * TVP;
        unsigned short* mm = Mm + (size_t)(layer * H + h) * BLK * MJP;
        for (int c = t; c < (BLK * TVP) / 8; c += 256)
            *(short8*)(tv + c * 8) = *(const short8*)&tvS[c * 8];
        for (int c = t; c < (BLK * MJP) / 8; c += 256)
            *(short8*)(mm + c * 8) = *(const short8*)&mmS[c * 8];
    } else {
        // ---- transpose x (B,L,H) fp32 -> u (B,H,L) bf16 : 64l x 32h tiles, 4096 blocks ----
        float* sh = (float*)smem_raw;        // [32*68]
        const int rb = bid - 1536;           // [0, 4096)
        const int hx = rb & 7, ly = (rb >> 3) & 63, b = rb >> 9;
        const int h0 = hx * 32, l0 = ly * 64;
        const int tx = t & 7, ty = t >> 3;   // load: tx = h-quad (8x float4 = 32 h), ty = l-row (32)
        const float* xb = x + ((size_t)b * L + l0) * H + h0;
#pragma unroll
        for (int i = 0; i < 2; ++i) {
            int l = ty + i * 32;
            float4 v = *(const float4*)(xb + (size_t)l * H + tx * 4);
            sh[(tx * 4 + 0) * 68 + l] = v.x;
            sh[(tx * 4 + 1) * 68 + l] = v.y;
            sh[(tx * 4 + 2) * 68 + l] = v.z;
            sh[(tx * 4 + 3) * 68 + l] = v.w;
        }
        __syncthreads();
        // write: 32 h-rows x 64 u16 (128B contiguous per row)
        const int hh = t >> 3, cc = (t & 7) * 8;
        const float* row = &sh[hh * 68 + cc];
        short8 o8;
#pragma unroll
        for (int j = 0; j < 8; ++j) o8[j] = (short)f2bf(row[j]);
        *(short8*)(u + ((size_t)b * H + h0 + hh) * L + l0 + cc) = o8;
    }
}

// ---------------- fused scan: GEMM-A + 2-level chain + GEMM-B (row-ownership, round-8 layout) ----------------
__global__ __launch_bounds__(256) void k_scan3(
    const unsigned short* __restrict__ u, const unsigned short* __restrict__ Mm_l,
    const unsigned short* __restrict__ TVc_l, const float2* __restrict__ w64c_l,
    unsigned short* __restrict__ y)
{
    __shared__ __align__(16) unsigned short uT[BLK * UTP];   // 9.2 KB
    __shared__ __align__(16) unsigned short ST[BLK * UTP];   // 9.2 KB
    __shared__ __align__(16) float INC[BLK * INP];           // 17.4 KB
    __shared__ float2 cLd[4][32];
    const int t = threadIdx.x;
    const int wv = t >> 6, lane = t & 63;
    const int lanei = lane & 15, quad = lane >> 4;
    // XCD-sharing decomposition: h = bid&255 puts the 8 batch-siblings that read
    // the same Mm[h]/TVc[h] on the same XCD residue (256%8==0) -> mats L2-shared.
    const int h = blockIdx.x & 255, ct = blockIdx.x >> 8;    // ct = batch
    const unsigned short* ub = u + (size_t)(ct * H + h) * L;

    // early register prefetch of all mats operands (hides L2/HBM latency under
    // staging + scan; hipcc won't hoist loads across __syncthreads)
    const unsigned short* arowA = Mm_l + (size_t)h * BLK * MJP + (wv * 16 + lanei) * MJP + quad * 8;
    short8 mA[2];
    mA[0] = *(const short8*)(arowA);
    mA[1] = *(const short8*)(arowA + 32);
    const unsigned short* arowB = TVc_l + (size_t)h * BLK * TVP + (wv * 16 + lanei) * TVP + quad * 8;
    short8 tB[4];
#pragma unroll
    for (int kt = 0; kt < 4; ++kt)
        tB[kt] = *(const short8*)(arowB + kt * 32);
    const float2 w64 = w64c_l[h * N2 + (lane & 31)];

    {   // stage uT[col=blk][j] bf16 (direct copy)
        int col = t >> 2, q = t & 3;
        *(short8*)&uT[col * UTP + q * 16]     = *(const short8*)(ub + col * 64 + q * 16);
        *(short8*)&uT[col * UTP + q * 16 + 8] = *(const short8*)(ub + col * 64 + q * 16 + 8);
    }
    __syncthreads();

    // ---- GEMM-A: INC[blk][k] = sum_j M[k][j] * u[blk*64+j] ----
    {
        f32x4 acc[4];
#pragma unroll
        for (int nt = 0; nt < 4; ++nt) acc[nt] = (f32x4){0.f, 0.f, 0.f, 0.f};
#pragma unroll
        for (int kt = 0; kt < 2; ++kt) {
#pragma unroll
            for (int nt = 0; nt < 4; ++nt) {
                short8 b8 = *(const short8*)&uT[(nt * 16 + lanei) * UTP + kt * 32 + quad * 8];
                acc[nt] = __builtin_amdgcn_mfma_f32_16x16x32_bf16(mA[kt], b8, acc[nt], 0, 0, 0);
            }
        }
#pragma unroll
        for (int nt = 0; nt < 4; ++nt)
            *(f32x4*)&INC[(nt * 16 + lanei) * INP + wv * 16 + quad * 4] = acc[nt];
    }
    __syncthreads();

    // ---- chain: two-level parallel scan (each wave owns 16 blocks) ----
    const int n = lane & 31;
    float Pr[16], Pi[16];
    float w1r = 1.f, w1i = 0.f;
    if (lane < 32) {
        float sr = 0.f, si = 0.f;
        const int base = wv * 16;
#pragma unroll
        for (int k = 0; k < 16; ++k) {
            Pr[k] = sr; Pi[k] = si;
            float ir = INC[(base + k) * INP + n];
            float ii = INC[(base + k) * INP + 32 + n];
            float nr = fmaf(w64.x, sr, fmaf(-w64.y, si, ir));
            float ni = fmaf(w64.x, si, fmaf(w64.y, sr, ii));
            sr = nr; si = ni;
        }
        cLd[wv][n] = make_float2(sr, si);
        float ar = w64.x, ai = w64.y;
#pragma unroll
        for (int q = 0; q < 4; ++q) {         // w64^16
            float nr2 = ar * ar - ai * ai;
            float ni2 = 2.f * ar * ai;
            ar = nr2; ai = ni2;
        }
        w1r = ar; w1i = ai;
    }
    __syncthreads();
    if (lane < 32) {
        float Cr = 0.f, Ci = 0.f;
        for (int wp = 0; wp < wv; ++wp) {
            float2 Lw = cLd[wp][n];
            float nr = fmaf(w1r, Cr, fmaf(-w1i, Ci, Lw.x));
            float ni = fmaf(w1r, Ci, fmaf(w1i, Cr, Lw.y));
            Cr = nr; Ci = ni;
        }
        float pr = 1.f, pi = 0.f;
#pragma unroll
        for (int k = 0; k < 16; ++k) {
            int blk = wv * 16 + k;
            float Sr = fmaf(pr, Cr, fmaf(-pi, Ci, Pr[k]));
            float Si = fmaf(pr, Ci, fmaf(pi, Cr, Pi[k]));
            ST[blk * UTP + n]      = f2bf(Sr);
            ST[blk * UTP + 32 + n] = f2bf(Si);
            float npr = pr * w64.x - pi * w64.y;
            float npi = pr * w64.y + pi * w64.x;
            pr = npr; pi = npi;
        }
    }
    __syncthreads();

    // ---- GEMM-B: y = gelu(T*U + Vc*S); restage via uT -> coalesced 16B stores ----
    {
        f32x4 acc[4];
#pragma unroll
        for (int nt = 0; nt < 4; ++nt) acc[nt] = (f32x4){0.f, 0.f, 0.f, 0.f};
#pragma unroll
        for (int kt = 0; kt < 4; ++kt) {
            const unsigned short* bb = (kt < 2) ? uT : ST;
            int ko = (kt & 1) * 32 + quad * 8;
#pragma unroll
            for (int nt = 0; nt < 4; ++nt) {
                short8 b8 = *(const short8*)&bb[(nt * 16 + lanei) * UTP + ko];
                acc[nt] = __builtin_amdgcn_mfma_f32_16x16x32_bf16(tB[kt], b8, acc[nt], 0, 0, 0);
            }
        }
        __syncthreads();   // all waves done reading uT -> safe to reuse
#pragma unroll
        for (int nt = 0; nt < 4; ++nt) {
            int blk = nt * 16 + lanei;
            int i0 = wv * 16 + quad * 4;
            ushort4 o4;
            o4.x = f2bf(gelu_f(acc[nt][0]));
            o4.y = f2bf(gelu_f(acc[nt][1]));
            o4.z = f2bf(gelu_f(acc[nt][2]));
            o4.w = f2bf(gelu_f(acc[nt][3]));
            *(ushort4*)&uT[blk * UTP + i0] = o4;
        }
        __syncthreads();
        unsigned short* yb = y + (size_t)(ct * H + h) * L;
#pragma unroll
        for (int r = 0; r < 2; ++r) {
            int c = r * 256 + t;             // 512 chunks = 64 blk x 8
            int o = c >> 3, c8 = (c & 7) * 8;
            *(short8*)(yb + o * 64 + c8) = *(const short8*)&uT[o * UTP + c8];
        }
    }
}

// ---------------- MFMA GEMM + bias + GLU + residual + channel-LN: dual-tile ----------------
// Grid 256, launch_bounds(512,2). LDS trimmed 90.6->75.8 KB (residual tile stride
// 64 + XOR swizzle col^((o&7)<<3) instead of pad-to-72): if occupancy was
// LDS-capped this yields 2 blocks/CU; if the unified 256-reg/wave footprint
// (128 arch + 128 acc) is the cap, occupancy stays ~20% and next step pivots.
__global__ __launch_bounds__(512, 2) void k_gemm(
    const unsigned short* __restrict__ y, unsigned short* __restrict__ u,
    const unsigned short* __restrict__ Wb, const float* __restrict__ bo,
    const float* __restrict__ lng, const float* __restrict__ lnb,
    float* __restrict__ outp)
{
    __shared__ __align__(16) unsigned short ySA[YSZ];         // 33.8 KB
    __shared__ __align__(16) unsigned short ySB[YSZ];         // 33.8 KB
    __shared__ float bS[O2];
    __shared__ float lgS[H], lbS[H];
    __shared__ float redS[8][4][16], redQ[8][4][16];

    const int t = threadIdx.x;
    const int wv = t >> 6;
    const int lane = t & 63;
    const int lanei = lane & 15;
    const int quad = lane >> 4;
    const int idxA = blockIdx.x;             // tile A
    const int idxB = blockIdx.x + 256;       // tile B
    const int bA = idxA >> 6, l0A = (idxA & 63) * TL2;
    const int bB = idxB >> 6, l0B = (idxB & 63) * TL2;

    size_t abase[2][2];
#pragma unroll
    for (int p = 0; p < 2; ++p)
#pragma unroll
        for (int jj = 0; jj < 2; ++jj)
            abase[p][jj] = (size_t)(p * 256 + wv * 32 + jj * 16 + lanei) * H + quad * 8;

    {   // stage BOTH y tiles (256h x 64l bf16 each) -> ySx[l][h ^ 8*(l>>3)] (swizzled)
        const int i = t & 7, hr = t >> 3;    // i: l-octet 0..7, hr: 0..63
        const unsigned short* ybA = y + (size_t)bA * H * L + l0A + i * 8;
        const unsigned short* ybB = y + (size_t)bB * H * L + l0B + i * 8;
        short8 vA[4], vB[4];
#pragma unroll
        for (int ps = 0; ps < 4; ++ps)
            vA[ps] = *(const short8*)(ybA + (size_t)(ps * 64 + hr) * L);
#pragma unroll
        for (int ps = 0; ps < 4; ++ps)
            vB[ps] = *(const short8*)(ybB + (size_t)(ps * 64 + hr) * L);
#pragma unroll
        for (int ps = 0; ps < 4; ++ps) {
            int h = ps * 64 + hr;
#pragma unroll
            for (int r = 0; r < 8; ++r)
                ySA[(i * 8 + r) * YPAD + (h ^ (8 * i))] = (unsigned short)vA[ps][r];
        }
#pragma unroll
        for (int ps = 0; ps < 4; ++ps) {
            int h = ps * 64 + hr;
#pragma unroll
            for (int r = 0; r < 8; ++r)
                ySB[(i * 8 + r) * YPAD + (h ^ (8 * i))] = (unsigned short)vB[ps][r];
        }
        if (t < O2) bS[t] = bo[t];
        if (t < H) { lgS[t] = lng[t]; lbS[t] = lnb[t]; }
    }
    __syncthreads();

    f32x4 accA[2][2][4], accB[2][2][4];
#pragma unroll
    for (int p = 0; p < 2; ++p)
#pragma unroll
        for (int jj = 0; jj < 2; ++jj)
#pragma unroll
            for (int nt = 0; nt < 4; ++nt) {
                accA[p][jj][nt] = (f32x4){0.f, 0.f, 0.f, 0.f};
                accB[p][jj][nt] = (f32x4){0.f, 0.f, 0.f, 0.f};
            }

    // joint MFMA loop: one W-fragment batch per kt drives both tiles
#pragma unroll
    for (int kt = 0; kt < 8; ++kt) {
        short8 a8[4];
#pragma unroll
        for (int q = 0; q < 4; ++q)
            a8[q] = *(const short8*)(Wb + abase[q >> 1][q & 1] + kt * 32);
        short8 bfrA[4], bfrB[4];
#pragma unroll
        for (int nt = 0; nt < 4; ++nt) {
            int lp = nt * 16 + lanei;
            int a = (2 * nt + (lanei >> 3)) & 7;
            int off = lp * YPAD + ((kt * 32 + quad * 8) ^ (8 * a));
            bfrA[nt] = *(const short8*)&ySA[off];
            bfrB[nt] = *(const short8*)&ySB[off];
        }
#pragma unroll
        for (int p = 0; p < 2; ++p)
#pragma unroll
            for (int jj = 0; jj < 2; ++jj) {
#pragma unroll
                for (int nt = 0; nt < 4; ++nt) {
                    accA[p][jj][nt] = __builtin_amdgcn_mfma_f32_16x16x32_bf16(
                        a8[p * 2 + jj], bfrA[nt], accA[p][jj][nt], 0, 0, 0);
                    accB[p][jj][nt] = __builtin_amdgcn_mfma_f32_16x16x32_bf16(
                        a8[p * 2 + jj], bfrB[nt], accB[p][jj][nt], 0, 0, 0);
                }
            }
    }

    // ---- residual staging A (issue loads, then LDS write after barrier) ----
    // residual layout: yS[o*64 + (col ^ ((o&7)<<3))] — stride 64, XOR swizzle
    unsigned short* ubA = u + (size_t)bA * H * L + l0A;
    unsigned short* ubB = u + (size_t)bB * H * L + l0B;
    short8 rA[4];
#pragma unroll
    for (int r = 0; r < 4; ++r) {
        int c = r * 512 + t;
        int o = c >> 3, c8 = (c & 7) * 8;
        rA[r] = *(const short8*)(ubA + (size_t)o * L + c8);
    }
    __syncthreads();   // all waves done reading ySA/ySB -> safe to reuse
#pragma unroll
    for (int r = 0; r < 4; ++r) {
        int c = r * 512 + t;
        int o = c >> 3, c8 = (c & 7) * 8;
        *(short8*)&ySA[o * 64 + (c8 ^ ((o & 7) << 3))] = rA[r];
    }
    // issue residual B loads now: in flight across epilogue A
    short8 rB[4];
#pragma unroll
    for (int r = 0; r < 4; ++r) {
        int c = r * 512 + t;
        int o = c >> 3, c8 = (c & 7) * 8;
        rB[r] = *(const short8*)(ubB + (size_t)o * L + c8);
    }
    __syncthreads();

    // =========== epilogue A ===========
    {
        float psum[4] = {0.f, 0.f, 0.f, 0.f}, psq[4] = {0.f, 0.f, 0.f, 0.f};
#pragma unroll
        for (int jj = 0; jj < 2; ++jj) {
#pragma unroll
            for (int nt = 0; nt < 4; ++nt) {
                int lc = nt * 16 + lanei;
#pragma unroll
                for (int reg = 0; reg < 4; ++reg) {
                    int o = wv * 32 + jj * 16 + quad * 4 + reg;
                    float a = accA[0][jj][nt][reg] + bS[o];
                    float g = accA[1][jj][nt][reg] + bS[o + 256];
                    float glu = a / (1.f + __expf(-g));
                    float val = glu + bf2f(ySA[o * 64 + (lc ^ ((o & 7) << 3))]);
                    accA[0][jj][nt][reg] = val;
                    psum[nt] += val;
                    psq[nt] = fmaf(val, val, psq[nt]);
                }
            }
        }
#pragma unroll
        for (int nt = 0; nt < 4; ++nt) {
            psum[nt] += __shfl_xor(psum[nt], 16);
            psum[nt] += __shfl_xor(psum[nt], 32);
            psq[nt]  += __shfl_xor(psq[nt], 16);
            psq[nt]  += __shfl_xor(psq[nt], 32);
        }
        if (lane < 16) {
#pragma unroll
            for (int nt = 0; nt < 4; ++nt) {
                redS[wv][nt][lanei] = psum[nt];
                redQ[wv][nt][lanei] = psq[nt];
            }
        }
        __syncthreads();
        float mcol[4], icol[4];
#pragma unroll
        for (int nt = 0; nt < 4; ++nt) {
            float s = 0.f, q = 0.f;
#pragma unroll
            for (int w = 0; w < 8; ++w) { s += redS[w][nt][lanei]; q += redQ[w][nt][lanei]; }
            float m = s * (1.0f / 256.0f);
            float v = q * (1.0f / 256.0f) - m * m;
            mcol[nt] = m;
            icol[nt] = rsqrtf(v + 1e-5f);
        }
        if (outp == nullptr) {
#pragma unroll
            for (int jj = 0; jj < 2; ++jj) {
#pragma unroll
                for (int nt = 0; nt < 4; ++nt) {
                    int lc = nt * 16 + lanei;
#pragma unroll
                    for (int reg = 0; reg < 4; ++reg) {
                        int o = wv * 32 + jj * 16 + quad * 4 + reg;
                        float val = accA[0][jj][nt][reg];
                        float ov = (val - mcol[nt]) * icol[nt] * lgS[o] + lbS[o];
                        ySA[o * 64 + (lc ^ ((o & 7) << 3))] = f2bf(ov);
                    }
                }
            }
            __syncthreads();
#pragma unroll
            for (int r = 0; r < 4; ++r) {
                int c = r * 512 + t;
                int o = c >> 3, c8 = (c & 7) * 8;
                *(short8*)(ubA + (size_t)o * L + c8) = *(const short8*)&ySA[o * 64 + (c8 ^ ((o & 7) << 3))];
            }
        } else {
#pragma unroll
            for (int jj = 0; jj < 2; ++jj) {
#pragma unroll
                for (int nt = 0; nt < 4; ++nt) {
                    int lc = nt * 16 + lanei;
                    int o0 = wv * 32 + jj * 16 + quad * 4;
                    float4 ov;
#pragma unroll
                    for (int reg = 0; reg < 4; ++reg) {
                        int o = o0 + reg;
                        float val = accA[0][jj][nt][reg];
                        ((float*)&ov)[reg] = (val - mcol[nt]) * icol[nt] * lgS[o] + lbS[o];
                    }
                    *(float4*)(outp + ((size_t)bA * L + l0A + lc) * H + o0) = ov;
                }
            }
            __syncthreads();   // keep phase structure identical in both paths
        }
    }

    // ---- residual staging B ----
#pragma unroll
    for (int r = 0; r < 4; ++r) {
        int c = r * 512 + t;
        int o = c >> 3, c8 = (c & 7) * 8;
        *(short8*)&ySB[o * 64 + (c8 ^ ((o & 7) << 3))] = rB[r];
    }
    __syncthreads();

    // =========== epilogue B ===========
    {
        float psum[4] = {0.f, 0.f, 0.f, 0.f}, psq[4] = {0.f, 0.f, 0.f, 0.f};
#pragma unroll
        for (int jj = 0; jj < 2; ++jj) {
#pragma unroll
            for (int nt = 0; nt < 4; ++nt) {
                int lc = nt * 16 + lanei;
#pragma unroll
                for (int reg = 0; reg < 4; ++reg) {
                    int o = wv * 32 + jj * 16 + quad * 4 + reg;
                    float a = accB[0][jj][nt][reg] + bS[o];
                    float g = accB[1][jj][nt][reg] + bS[o + 256];
                    float glu = a / (1.f + __expf(-g));
                    float val = glu + bf2f(ySB[o * 64 + (lc ^ ((o & 7) << 3))]);
                    accB[0][jj][nt][reg] = val;
                    psum[nt] += val;
                    psq[nt] = fmaf(val, val, psq[nt]);
                }
            }
        }
#pragma unroll
        for (int nt = 0; nt < 4; ++nt) {
            psum[nt] += __shfl_xor(psum[nt], 16);
            psum[nt] += __shfl_xor(psum[nt], 32);
            psq[nt]  += __shfl_xor(psq[nt], 16);
            psq[nt]  += __shfl_xor(psq[nt], 32);
        }
        if (lane < 16) {
#pragma unroll
            for (int nt = 0; nt < 4; ++nt) {
                redS[wv][nt][lanei] = psum[nt];
                redQ[wv][nt][lanei] = psq[nt];
            }
        }
        __syncthreads();
        float mcol[4], icol[4];
#pragma unroll
        for (int nt = 0; nt < 4; ++nt) {
            float s = 0.f, q = 0.f;
#pragma unroll
            for (int w = 0; w < 8; ++w) { s += redS[w][nt][lanei]; q += redQ[w][nt][lanei]; }
            float m = s * (1.0f / 256.0f);
            float v = q * (1.0f / 256.0f) - m * m;
            mcol[nt] = m;
            icol[nt] = rsqrtf(v + 1e-5f);
        }
        if (outp == nullptr) {
#pragma unroll
            for (int jj = 0; jj < 2; ++jj) {
#pragma unroll
                for (int nt = 0; nt < 4; ++nt) {
                    int lc = nt * 16 + lanei;
#pragma unroll
                    for (int reg = 0; reg < 4; ++reg) {
                        int o = wv * 32 + jj * 16 + quad * 4 + reg;
                        float val = accB[0][jj][nt][reg];
                        float ov = (val - mcol[nt]) * icol[nt] * lgS[o] + lbS[o];
                        ySB[o * 64 + (lc ^ ((o & 7) << 3))] = f2bf(ov);
                    }
                }
            }
            __syncthreads();
#pragma unroll
            for (int r = 0; r < 4; ++r) {
                int c = r * 512 + t;
                int o = c >> 3, c8 = (c & 7) * 8;
                *(short8*)(ubB + (size_t)o * L + c8) = *(const short8*)&ySB[o * 64 + (c8 ^ ((o & 7) << 3))];
            }
        } else {
#pragma unroll
            for (int jj = 0; jj < 2; ++jj) {
#pragma unroll
                for (int nt = 0; nt < 4; ++nt) {
                    int lc = nt * 16 + lanei;
                    int o0 = wv * 32 + jj * 16 + quad * 4;
                    float4 ov;
#pragma unroll
                    for (int reg = 0; reg < 4; ++reg) {
                        int o = o0 + reg;
                        float val = accB[0][jj][nt][reg];
                        ((float*)&ov)[reg] = (val - mcol[nt]) * icol[nt] * lgS[o] + lbS[o];
                    }
                    *(float4*)(outp + ((size_t)bB * L + l0B + lc) * H + o0) = ov;
                }
            }
        }
    }
}

extern "C" void kernel_launch(void* const* d_in, const int* in_sizes, int n_in,
                              void* d_out, int out_size, void* d_ws, size_t ws_size,
                              hipStream_t stream)
{
    const float* x      = (const float*)d_in[0];
    const float* log_dt = (const float*)d_in[1];
    const float* log_Ar = (const float*)d_in[2];
    const float* A_im   = (const float*)d_in[3];
    const float* C_re   = (const float*)d_in[4];
    const float* C_im   = (const float*)d_in[5];
    const float* Dv     = (const float*)d_in[6];
    const float* Wout   = (const float*)d_in[7];
    const float* bout   = (const float*)d_in[8];
    const float* lng    = (const float*)d_in[9];
    const float* lnb    = (const float*)d_in[10];
    float* out = (float*)d_out;

    unsigned short* u   = (unsigned short*)d_ws;                          // 16.8 MB
    unsigned short* Wb  = u + (size_t)B * H * L;                          // 1 MB
    unsigned short* TVc = Wb + (size_t)NL * O2 * H;                       // 17.8 MB
    unsigned short* Mm  = TVc + (size_t)NL * H * BLK * TVP;               // 9.4 MB
    float2* w64c        = (float2*)(Mm + (size_t)NL * H * BLK * MJP);     // 0.26 MB
    unsigned short* y   = (unsigned short*)(w64c + (size_t)NL * H * N2);  // 16.8 MB

    // 512 wcvt + 1024 mats + 4096 tr_xu blocks
    k_setup<<<5632, 256, 0, stream>>>(x, log_dt, log_Ar, A_im, C_re, C_im, Dv, Wout,
                                      Wb, TVc, Mm, w64c, u);
    for (int layer = 0; layer < NL; ++layer) {
        k_scan3<<<H * 8, 256, 0, stream>>>(u, Mm + (size_t)layer * H * BLK * MJP,
                                           TVc + (size_t)layer * H * BLK * TVP,
                                           w64c + (size_t)layer * H * N2, y);
        k_gemm<<<256, 512, 0, stream>>>(y, u, Wb + (size_t)layer * O2 * H,
                                        bout + layer * O2, lng + layer * H, lnb + layer * H,
                                        (layer == NL - 1) ? out : nullptr);
    }
}